// Round 18
// baseline (221.630 us; speedup 1.0000x reference)
//
#include <hip/hip_runtime.h>
#include <hip/hip_bf16.h>

#define NN 50000
#define NE 500000
#define INDIM 128
#define NH 8
#define DH 32
#define HD 256
#define NPERM 100
#define NB_G 64
#define NC 10
#define SLOPE 0.2f
#define BCAP 64   // bucket capacity per node; Poisson(10) max over 50K nodes ~32, 2x margin

typedef short bf16x8 __attribute__((ext_vector_type(8)));
typedef float f32x4 __attribute__((ext_vector_type(4)));

__device__ inline float bf2f(unsigned short u) {
    union { unsigned int i; float f; } x; x.i = ((unsigned int)u) << 16; return x.f;
}
__device__ inline unsigned short f2bf(float f) {
    __hip_bfloat16 h = __float2bfloat16(f);
    return *reinterpret_cast<unsigned short*>(&h);
}

// ---------------- prep: zero counts + weight transpose + hg zero ----------------

#define NB_CNT ((NN + 255) / 256)   // 196

__global__ __launch_bounds__(256) void prep_kernel(
    int* __restrict__ counts,
    const float* __restrict__ W1, const float* __restrict__ W2,
    __hip_bfloat16* __restrict__ Wt1, __hip_bfloat16* __restrict__ Wt2,
    float* __restrict__ hg)
{
    int b = blockIdx.x;
    int c = threadIdx.x;
    if (b < NB_CNT) {
        int i = b * 256 + c;
        if (i < NN) counts[i] = 0;
    } else {
        int bb = b - NB_CNT;   // 0..383
        if (bb < INDIM) {
            Wt1[(size_t)c * INDIM + bb] = __float2bfloat16(W1[(size_t)bb * HD + c]);
        } else {
            int k = bb - INDIM;
            Wt2[(size_t)c * HD + k] = __float2bfloat16(W2[(size_t)k * HD + c]);
        }
        if (bb < NB_G) hg[bb * HD + c] = 0.f;
    }
}

// ---------------- MFMA GEMM: 64 rows x 256 cols, 512 threads / 8 waves ----------------
// R17 postmortem: 256-thr/4-wave blocks stall at 17% occupancy (12 waves/CU available);
// 512-thr blocks with per-wave work HALVED double the wave count to ~24/CU for latency hiding.
// Wave wc (0..7) owns the 32-col strip of head wc: acc[4][2] (32 VGPR).
// Whole 64 x K X-panel staged once (16/32 KB LDS), ONE barrier, unrolled MFMA loop.
// A from LDS (slot p = logical q ^ (row&7)); B streamed from L2-resident Wt.
// Blocks >= gemm_nblocks run the edge->bucket scatter (independent, overlapped).

template<int KVAL, int IS_F32>
__global__ __launch_bounds__(512) void gemm_mfma_kernel(
    const void* __restrict__ Xv, const __hip_bfloat16* __restrict__ Wt,
    const float* __restrict__ al, const float* __restrict__ ar,
    __hip_bfloat16* __restrict__ zb, float* __restrict__ el, float* __restrict__ er,
    int nrows, int gemm_nblocks,
    const int* __restrict__ dstv, const int* __restrict__ srcv,
    int* __restrict__ counts, int* __restrict__ bucket, int ne)
{
    __shared__ __attribute__((aligned(16))) unsigned short Xs[64 * KVAL];   // 16/32 KB
    int t = threadIdx.x;

    if ((int)blockIdx.x >= gemm_nblocks) {
        // fused bucket scatter (block-uniform branch; never reaches the barrier)
        int e = ((int)blockIdx.x - gemm_nblocks) * 512 + t;
        if (e < ne) {
            int d = dstv[e];
            int p = atomicAdd(&counts[d], 1);
            if (p < BCAP) bucket[(size_t)d * BCAP + p] = srcv[e];
        }
        return;
    }

    int l = t & 63;
    int wc = t >> 6;        // wave 0..7 -> head wc, cols [wc*32, wc*32+32)
    int nb = blockIdx.x * 64;
    int wcb = wc * 32;
    int lg = l >> 4;
    int lr = l & 15;

    const short* Wt16 = (const short*)Wt;
    constexpr int NSLOT = KVAL / 8;       // 16B slots per row (16 or 32)
    constexpr int NKK = KVAL / 32;        // MFMA k-steps (4 or 8)

    // ---- stage entire X panel (single shot) ----
    if (IS_F32) {
        // fp32 -> bf16 register staging: thread t owns row t>>3, slots (t&7)+8i
        const float* Xf = (const float*)Xv;
        int row = t >> 3;
        int gr = nb + row;
#pragma unroll
        for (int i = 0; i < NSLOT / 8; ++i) {
            int j = (t & 7) + 8 * i;
            bf16x8 xv = {0, 0, 0, 0, 0, 0, 0, 0};
            if (gr < nrows) {
                const float* p = &Xf[(size_t)gr * KVAL + j * 8];
                float4 xa = *(const float4*)&p[0];
                float4 xb = *(const float4*)&p[4];
                xv[0] = (short)f2bf(xa.x); xv[1] = (short)f2bf(xa.y);
                xv[2] = (short)f2bf(xa.z); xv[3] = (short)f2bf(xa.w);
                xv[4] = (short)f2bf(xb.x); xv[5] = (short)f2bf(xb.y);
                xv[6] = (short)f2bf(xb.z); xv[7] = (short)f2bf(xb.w);
            }
            *(bf16x8*)&Xs[row * KVAL + ((j ^ (row & 7)) * 8)] = xv;
        }
    } else {
        // bf16: global_load_lds, linear LDS dest, pre-swizzled global source
        const short* X16 = (const short*)Xv;
#pragma unroll
        for (int i = 0; i < (64 * NSLOT) / 512; ++i) {
            int c = t + i * 512;
            int row = c / NSLOT;
            int p = c % NSLOT;
            int q = p ^ (row & 7);
            const short* ga = &X16[(size_t)(nb + row) * KVAL + q * 8];
            __builtin_amdgcn_global_load_lds(
                (const __attribute__((address_space(1))) void*)ga,
                (__attribute__((address_space(3))) void*)((char*)Xs + (size_t)c * 16), 16, 0, 0);
        }
    }
    __syncthreads();   // the single barrier

    // ---- MFMA loop, no barriers; acc[4][2] = 32 VGPR ----
    f32x4 acc[4][2];
#pragma unroll
    for (int rb = 0; rb < 4; ++rb)
#pragma unroll
        for (int cf = 0; cf < 2; ++cf) acc[rb][cf] = (f32x4){0.f, 0.f, 0.f, 0.f};

#pragma unroll
    for (int kk = 0; kk < NKK; ++kk) {
        bf16x8 b[2], a[4];
#pragma unroll
        for (int cf = 0; cf < 2; ++cf) {
            int col = wcb + cf * 16 + lr;
            b[cf] = *(const bf16x8*)&Wt16[(size_t)col * KVAL + kk * 32 + lg * 8];
        }
#pragma unroll
        for (int rb = 0; rb < 4; ++rb) {
            int row = rb * 16 + lr;
            int slot = (kk * 4 + lg) ^ (row & 7);
            a[rb] = *(const bf16x8*)&Xs[row * KVAL + slot * 8];
        }
#pragma unroll
        for (int rb = 0; rb < 4; ++rb)
#pragma unroll
            for (int cf = 0; cf < 2; ++cf)
                acc[rb][cf] = __builtin_amdgcn_mfma_f32_16x16x32_bf16(a[rb], b[cf], acc[rb][cf], 0, 0, 0);
    }

    // ---- epilogue: direct stores ----
    float al_c[2], ar_c[2];
#pragma unroll
    for (int cf = 0; cf < 2; ++cf) {
        al_c[cf] = al[wcb + cf * 16 + lr];
        ar_c[cf] = ar[wcb + cf * 16 + lr];
    }

    unsigned short* zu = (unsigned short*)zb;
#pragma unroll
    for (int rb = 0; rb < 4; ++rb) {
        int rbase = nb + rb * 16 + lg * 4;
#pragma unroll
        for (int j = 0; j < 4; ++j) {
            int r = rbase + j;
            if (r < nrows) {
#pragma unroll
                for (int cf = 0; cf < 2; ++cf)
                    zu[(size_t)r * HD + wcb + cf * 16 + lr] = f2bf(acc[rb][cf][j]);
            }
        }
        // el/er: wave wc covers exactly head wc (cols wc*32..wc*32+31)
        float p[4], q[4];
#pragma unroll
        for (int j = 0; j < 4; ++j) {
            p[j] = acc[rb][0][j] * al_c[0] + acc[rb][1][j] * al_c[1];
            q[j] = acc[rb][0][j] * ar_c[0] + acc[rb][1][j] * ar_c[1];
        }
#pragma unroll
        for (int m = 1; m < 16; m <<= 1) {
#pragma unroll
            for (int j = 0; j < 4; ++j) {
                p[j] += __shfl_xor(p[j], m);
                q[j] += __shfl_xor(q[j], m);
            }
        }
        if (lr == 0) {
#pragma unroll
            for (int j = 0; j < 4; ++j) {
                int r = rbase + j;
                if (r < nrows) {
                    el[(size_t)r * NH + wc] = p[j];
                    er[(size_t)r * NH + wc] = q[j];
                }
            }
        }
    }
}

// ---------------- per-dst-node attention aggregate (R9 structure = proven floor) ----------------

__global__ __launch_bounds__(256) void agg_kernel(
    const __hip_bfloat16* __restrict__ zb, const float* __restrict__ el, const float* __restrict__ er,
    const float* __restrict__ bias, const int* __restrict__ counts,
    const int* __restrict__ bucket, __hip_bfloat16* __restrict__ out, int nrows, int do_relu)
{
    int wid = (blockIdx.x * 256 + threadIdx.x) >> 6;
    int l = threadIdx.x & 63;
    if (wid >= nrows) return;   // wave-uniform
    int n = wid;
    int K = counts[n];
    if (K > BCAP) K = BCAP;
    const int* srcs = &bucket[(size_t)n * BCAP];
    const unsigned short* zu = (const unsigned short*)zb;

    int es = l >> 4;   // edge slot 0..3
    int li = l & 15;   // channel group: c0 = li*16
    int hh = li >> 1;  // head
    float ern = er[(size_t)n * NH + hh];
    int c0 = li * 16;

    float num[16];
#pragma unroll
    for (int j = 0; j < 16; ++j) num[j] = 0.f;
    float den = 0.f;

    for (int kb = 0; kb < K; kb += 4) {
        int k = kb + es;
        if (k < K) {
            int s = srcs[k];
            float v = el[(size_t)s * NH + hh] + ern;
            v = v > 0.f ? v : SLOPE * v;
            float w = __expf(v);
            den += w;
            const unsigned short* zr = &zu[(size_t)s * HD + c0];
            bf16x8 z0 = *(const bf16x8*)&zr[0];
            bf16x8 z1 = *(const bf16x8*)&zr[8];
#pragma unroll
            for (int j = 0; j < 8; ++j) {
                num[j]     += w * bf2f((unsigned short)z0[j]);
                num[8 + j] += w * bf2f((unsigned short)z1[j]);
            }
        }
    }

    den += __shfl_xor(den, 16);
    den += __shfl_xor(den, 32);
#pragma unroll
    for (int j = 0; j < 16; ++j) {
        num[j] += __shfl_xor(num[j], 16);
        num[j] += __shfl_xor(num[j], 32);
    }

    if (es == 0) {
        float inv = (K > 0) ? 1.0f / den : 0.f;   // deg-0 node -> out = bias
        unsigned short* op = (unsigned short*)out;
        float4 bva = *(const float4*)&bias[c0];
        float4 bvb = *(const float4*)&bias[c0 + 4];
        float4 bvc = *(const float4*)&bias[c0 + 8];
        float4 bvd = *(const float4*)&bias[c0 + 12];
        float bb[16] = {bva.x, bva.y, bva.z, bva.w, bvb.x, bvb.y, bvb.z, bvb.w,
                        bvc.x, bvc.y, bvc.z, bvc.w, bvd.x, bvd.y, bvd.z, bvd.w};
        bf16x8 o0, o1;
#pragma unroll
        for (int j = 0; j < 8; ++j) {
            float v0 = num[j] * inv + bb[j];
            float v1 = num[8 + j] * inv + bb[8 + j];
            if (do_relu) { v0 = fmaxf(v0, 0.f); v1 = fmaxf(v1, 0.f); }
            o0[j] = (short)f2bf(v0);
            o1[j] = (short)f2bf(v1);
        }
        *(bf16x8*)&op[(size_t)n * HD + c0] = o0;
        *(bf16x8*)&op[(size_t)n * HD + c0 + 8] = o1;
    }
}

// ---------------- readout ----------------

__global__ __launch_bounds__(256) void graph_sum_kernel(
    const __hip_bfloat16* __restrict__ h2, const int* __restrict__ gids,
    float* __restrict__ hg)
{
    int c = threadIdx.x;
    int n0 = blockIdx.x * 64;
    int n1 = n0 + 64;
    if (n0 >= NN) return;
    if (n1 > NN) n1 = NN;
    const unsigned short* hu = (const unsigned short*)h2;
    float acc = 0.f;
    int cur = gids[n0];
    for (int n = n0; n < n1; ++n) {
        int g = gids[n];
        if (g != cur) {
            atomicAdd(&hg[cur * HD + c], acc);
            acc = 0.f;
            cur = g;
        }
        acc += bf2f(hu[(size_t)n * HD + c]);
    }
    atomicAdd(&hg[cur * HD + c], acc);
}

__global__ void classifier_kernel(const float* __restrict__ hg, const float* __restrict__ perm,
                                  const float* __restrict__ Wc, const float* __restrict__ bc,
                                  const int* __restrict__ gids, float* __restrict__ out) {
    int g = blockIdx.x;
    int c = threadIdx.x;
    if (c >= NC) return;
    int lo = 0, hi = NN;
    while (lo < hi) { int mid = (lo + hi) >> 1; if (gids[mid] < g) lo = mid + 1; else hi = mid; }
    int s0 = lo;
    lo = 0; hi = NN;
    while (lo < hi) { int mid = (lo + hi) >> 1; if (gids[mid] < g + 1) lo = mid + 1; else hi = mid; }
    float cnt = fmaxf((float)(lo - s0), 1.0f);
    float inv = 1.0f / cnt;
    float sg = 0.f;
    for (int k = 0; k < HD; ++k) sg += hg[g * HD + k] * Wc[k * NC + c];
    float s = bc[c] + sg * inv;
    for (int k = 0; k < NPERM; ++k) s += perm[g * NPERM + k] * Wc[(HD + k) * NC + c];
    out[g * NC + c] = s;
}

// ---------------- launch ----------------

extern "C" void kernel_launch(void* const* d_in, const int* in_sizes, int n_in,
                              void* d_out, int out_size, void* d_ws, size_t ws_size,
                              hipStream_t stream) {
    const float* h    = (const float*)d_in[0];
    const float* perm = (const float*)d_in[1];
    const float* W1   = (const float*)d_in[2];
    const float* al1  = (const float*)d_in[3];
    const float* ar1  = (const float*)d_in[4];
    const float* b1   = (const float*)d_in[5];
    const float* W2   = (const float*)d_in[6];
    const float* al2  = (const float*)d_in[7];
    const float* ar2  = (const float*)d_in[8];
    const float* b2   = (const float*)d_in[9];
    const float* Wc   = (const float*)d_in[10];
    const float* bc   = (const float*)d_in[11];
    const int* src    = (const int*)d_in[12];
    const int* dst    = (const int*)d_in[13];
    const int* gids   = (const int*)d_in[14];
    float* out = (float*)d_out;

    __hip_bfloat16* zb  = (__hip_bfloat16*)d_ws;                  // N*256
    __hip_bfloat16* h1b = zb + (size_t)NN * HD;                   // N*256
    __hip_bfloat16* Wt1 = h1b + (size_t)NN * HD;                  // 256*128
    __hip_bfloat16* Wt2 = Wt1 + (size_t)HD * INDIM;               // 256*256
    float* el = (float*)(Wt2 + (size_t)HD * HD);                  // N*8
    float* er = el + (size_t)NN * NH;                             // N*8
    float* hg = er + (size_t)NN * NH;                             // B*256
    int* counts = (int*)(hg + NB_G * HD);                         // N
    int* bucket = counts + NN;                                    // N*BCAP (12.8 MB)

    int nblocks_e512 = (NE + 511) / 512;   // 977 scatter blocks (512 thr)
    int gemm_blocks = (NN + 63) / 64;      // 782
    int wave_node_blocks = (NN * 64 + 255) / 256;

    // prep: zero counts + transpose weights + zero hg
    prep_kernel<<<NB_CNT + INDIM + HD, 256, 0, stream>>>(counts, W1, W2, Wt1, Wt2, hg);

    // layer-1 gemm (K=128, fp32 input) with fused bucket scatter
    gemm_mfma_kernel<INDIM, 1><<<gemm_blocks + nblocks_e512, 512, 0, stream>>>(
        h, Wt1, al1, ar1, zb, el, er, NN,
        gemm_blocks, dst, src, counts, bucket, NE);
    agg_kernel<<<wave_node_blocks, 256, 0, stream>>>(zb, el, er, b1, counts, bucket, h1b, NN, 1);
    // layer 2 (K=256, bf16 input -> single-shot global_load_lds staging)
    gemm_mfma_kernel<HD, 0><<<gemm_blocks, 512, 0, stream>>>(
        h1b, Wt2, al2, ar2, zb, el, er, NN,
        gemm_blocks, nullptr, nullptr, nullptr, nullptr, 0);
    agg_kernel<<<wave_node_blocks, 256, 0, stream>>>(zb, el, er, b2, counts, bucket, h1b, NN, 0);

    // readout
    graph_sum_kernel<<<(NN + 63) / 64, 256, 0, stream>>>(h1b, gids, hg);
    classifier_kernel<<<NB_G, 64, 0, stream>>>(hg, perm, Wc, bc, gids, out);
}

// Round 19
// 211.468 us; speedup vs baseline: 1.0481x; 1.0481x over previous
//
#include <hip/hip_runtime.h>
#include <hip/hip_bf16.h>

#define NN 50000
#define NE 500000
#define INDIM 128
#define NH 8
#define DH 32
#define HD 256
#define NPERM 100
#define NB_G 64
#define NC 10
#define SLOPE 0.2f
#define BCAP 64   // bucket capacity per node; Poisson(10) max over 50K nodes ~32, 2x margin

typedef short bf16x8 __attribute__((ext_vector_type(8)));
typedef float f32x4 __attribute__((ext_vector_type(4)));

__device__ inline float bf2f(unsigned short u) {
    union { unsigned int i; float f; } x; x.i = ((unsigned int)u) << 16; return x.f;
}
__device__ inline unsigned short f2bf(float f) {
    __hip_bfloat16 h = __float2bfloat16(f);
    return *reinterpret_cast<unsigned short*>(&h);
}

// ---------------- prep: zero counts + weight transpose + hg zero ----------------

#define NB_CNT ((NN + 255) / 256)   // 196

__global__ __launch_bounds__(256) void prep_kernel(
    int* __restrict__ counts,
    const float* __restrict__ W1, const float* __restrict__ W2,
    __hip_bfloat16* __restrict__ Wt1, __hip_bfloat16* __restrict__ Wt2,
    float* __restrict__ hg)
{
    int b = blockIdx.x;
    int c = threadIdx.x;
    if (b < NB_CNT) {
        int i = b * 256 + c;
        if (i < NN) counts[i] = 0;
    } else {
        int bb = b - NB_CNT;   // 0..383
        if (bb < INDIM) {
            Wt1[(size_t)c * INDIM + bb] = __float2bfloat16(W1[(size_t)bb * HD + c]);
        } else {
            int k = bb - INDIM;
            Wt2[(size_t)c * HD + k] = __float2bfloat16(W2[(size_t)k * HD + c]);
        }
        if (bb < NB_G) hg[bb * HD + c] = 0.f;
    }
}

// ---------------- MFMA GEMM: 64 rows x 256 cols, 256 thr / 4 waves, whole-panel LDS ----------------
// R18 postmortem: VGPR_Count=36 -> compiler serialized every load (zero MLP); all pipes idle.
// This version FORCES memory-level parallelism: per 4-k-step half, hoist ALL 16 B-operand
// global loads + ALL 16 A ds_reads into register arrays (issued back-to-back, independent),
// then run 64 MFMAs. One vmcnt/lgkmcnt drain per half instead of per-MFMA.
// Whole 64 x K X-panel staged once (16/32 KB LDS), ONE barrier.
// Blocks >= gemm_nblocks run the edge->bucket scatter (independent, overlapped).

template<int KVAL, int IS_F32>
__global__ __launch_bounds__(256) void gemm_mfma_kernel(
    const void* __restrict__ Xv, const __hip_bfloat16* __restrict__ Wt,
    const float* __restrict__ al, const float* __restrict__ ar,
    __hip_bfloat16* __restrict__ zb, float* __restrict__ el, float* __restrict__ er,
    int nrows, int gemm_nblocks,
    const int* __restrict__ dstv, const int* __restrict__ srcv,
    int* __restrict__ counts, int* __restrict__ bucket, int ne)
{
    __shared__ __attribute__((aligned(16))) unsigned short Xs[64 * KVAL];   // 16/32 KB
    int t = threadIdx.x;

    if ((int)blockIdx.x >= gemm_nblocks) {
        // fused bucket scatter (block-uniform branch; never reaches the barrier)
        int e = ((int)blockIdx.x - gemm_nblocks) * 256 + t;
        if (e < ne) {
            int d = dstv[e];
            int p = atomicAdd(&counts[d], 1);
            if (p < BCAP) bucket[(size_t)d * BCAP + p] = srcv[e];
        }
        return;
    }

    int l = t & 63;
    int wc = t >> 6;        // 0..3 -> cols [wc*64, wc*64+64)
    int nb = blockIdx.x * 64;
    int wcb = wc * 64;
    int lg = l >> 4;
    int lr = l & 15;

    const short* Wt16 = (const short*)Wt;
    constexpr int NSLOT = KVAL / 8;       // 16B slots per row (16 or 32)
    constexpr int NKK = KVAL / 32;        // MFMA k-steps (4 or 8)
    constexpr int HALF = 4;               // k-steps per hoisted batch

    // ---- stage entire X panel (single shot) ----
    if (IS_F32) {
        const float* Xf = (const float*)Xv;
        int row = t >> 2;
        int gr = nb + row;
#pragma unroll
        for (int i = 0; i < NSLOT / 4; ++i) {
            int j = (t & 3) + 4 * i;
            bf16x8 xv = {0, 0, 0, 0, 0, 0, 0, 0};
            if (gr < nrows) {
                const float* p = &Xf[(size_t)gr * KVAL + j * 8];
                float4 xa = *(const float4*)&p[0];
                float4 xb = *(const float4*)&p[4];
                xv[0] = (short)f2bf(xa.x); xv[1] = (short)f2bf(xa.y);
                xv[2] = (short)f2bf(xa.z); xv[3] = (short)f2bf(xa.w);
                xv[4] = (short)f2bf(xb.x); xv[5] = (short)f2bf(xb.y);
                xv[6] = (short)f2bf(xb.z); xv[7] = (short)f2bf(xb.w);
            }
            *(bf16x8*)&Xs[row * KVAL + ((j ^ (row & 7)) * 8)] = xv;
        }
    } else {
        const short* X16 = (const short*)Xv;
#pragma unroll
        for (int i = 0; i < (64 * NSLOT) / 256; ++i) {
            int c = t + i * 256;
            int row = c / NSLOT;
            int p = c % NSLOT;
            int q = p ^ (row & 7);
            const short* ga = &X16[(size_t)(nb + row) * KVAL + q * 8];
            __builtin_amdgcn_global_load_lds(
                (const __attribute__((address_space(1))) void*)ga,
                (__attribute__((address_space(3))) void*)((char*)Xs + (size_t)c * 16), 16, 0, 0);
        }
    }
    __syncthreads();   // the single barrier

    // ---- MFMA loop with forced MLP: batch-hoisted B (global) and A (LDS) per half ----
    f32x4 acc[4][4];
#pragma unroll
    for (int rb = 0; rb < 4; ++rb)
#pragma unroll
        for (int cf = 0; cf < 4; ++cf) acc[rb][cf] = (f32x4){0.f, 0.f, 0.f, 0.f};

#pragma unroll
    for (int h0 = 0; h0 < NKK; h0 += HALF) {
        bf16x8 bb[HALF][4];   // 16 independent global loads, issued back-to-back
#pragma unroll
        for (int kk = 0; kk < HALF; ++kk)
#pragma unroll
            for (int cf = 0; cf < 4; ++cf) {
                int col = wcb + cf * 16 + lr;
                bb[kk][cf] = *(const bf16x8*)&Wt16[(size_t)col * KVAL + (h0 + kk) * 32 + lg * 8];
            }
        bf16x8 aa[HALF][4];   // 16 independent ds_reads, issued back-to-back
#pragma unroll
        for (int kk = 0; kk < HALF; ++kk)
#pragma unroll
            for (int rb = 0; rb < 4; ++rb) {
                int row = rb * 16 + lr;
                int slot = ((h0 + kk) * 4 + lg) ^ (row & 7);
                aa[kk][rb] = *(const bf16x8*)&Xs[row * KVAL + slot * 8];
            }
#pragma unroll
        for (int kk = 0; kk < HALF; ++kk)
#pragma unroll
            for (int rb = 0; rb < 4; ++rb)
#pragma unroll
                for (int cf = 0; cf < 4; ++cf)
                    acc[rb][cf] = __builtin_amdgcn_mfma_f32_16x16x32_bf16(aa[kk][rb], bb[kk][cf], acc[rb][cf], 0, 0, 0);
    }

    // ---- epilogue: direct stores (R14/R17 form) ----
    float al_c[4], ar_c[4];
#pragma unroll
    for (int cf = 0; cf < 4; ++cf) {
        al_c[cf] = al[wcb + cf * 16 + lr];
        ar_c[cf] = ar[wcb + cf * 16 + lr];
    }

    unsigned short* zu = (unsigned short*)zb;
#pragma unroll
    for (int rb = 0; rb < 4; ++rb) {
        int rbase = nb + rb * 16 + lg * 4;
#pragma unroll
        for (int j = 0; j < 4; ++j) {
            int r = rbase + j;
            if (r < nrows) {
#pragma unroll
                for (int cf = 0; cf < 4; ++cf)
                    zu[(size_t)r * HD + wcb + cf * 16 + lr] = f2bf(acc[rb][cf][j]);
            }
        }
        float p0[4], p1[4], q0[4], q1[4];
#pragma unroll
        for (int j = 0; j < 4; ++j) {
            p0[j] = acc[rb][0][j] * al_c[0] + acc[rb][1][j] * al_c[1];
            p1[j] = acc[rb][2][j] * al_c[2] + acc[rb][3][j] * al_c[3];
            q0[j] = acc[rb][0][j] * ar_c[0] + acc[rb][1][j] * ar_c[1];
            q1[j] = acc[rb][2][j] * ar_c[2] + acc[rb][3][j] * ar_c[3];
        }
#pragma unroll
        for (int m = 1; m < 16; m <<= 1) {
#pragma unroll
            for (int j = 0; j < 4; ++j) {
                p0[j] += __shfl_xor(p0[j], m);
                p1[j] += __shfl_xor(p1[j], m);
                q0[j] += __shfl_xor(q0[j], m);
                q1[j] += __shfl_xor(q1[j], m);
            }
        }
        if (lr == 0) {
#pragma unroll
            for (int j = 0; j < 4; ++j) {
                int r = rbase + j;
                if (r < nrows) {
                    el[(size_t)r * NH + 2 * wc]     = p0[j];
                    el[(size_t)r * NH + 2 * wc + 1] = p1[j];
                    er[(size_t)r * NH + 2 * wc]     = q0[j];
                    er[(size_t)r * NH + 2 * wc + 1] = q1[j];
                }
            }
        }
    }
}

// ---------------- per-dst-node attention aggregate (R9 structure = proven floor) ----------------

__global__ __launch_bounds__(256) void agg_kernel(
    const __hip_bfloat16* __restrict__ zb, const float* __restrict__ el, const float* __restrict__ er,
    const float* __restrict__ bias, const int* __restrict__ counts,
    const int* __restrict__ bucket, __hip_bfloat16* __restrict__ out, int nrows, int do_relu)
{
    int wid = (blockIdx.x * 256 + threadIdx.x) >> 6;
    int l = threadIdx.x & 63;
    if (wid >= nrows) return;   // wave-uniform
    int n = wid;
    int K = counts[n];
    if (K > BCAP) K = BCAP;
    const int* srcs = &bucket[(size_t)n * BCAP];
    const unsigned short* zu = (const unsigned short*)zb;

    int es = l >> 4;   // edge slot 0..3
    int li = l & 15;   // channel group: c0 = li*16
    int hh = li >> 1;  // head
    float ern = er[(size_t)n * NH + hh];
    int c0 = li * 16;

    float num[16];
#pragma unroll
    for (int j = 0; j < 16; ++j) num[j] = 0.f;
    float den = 0.f;

    for (int kb = 0; kb < K; kb += 4) {
        int k = kb + es;
        if (k < K) {
            int s = srcs[k];
            float v = el[(size_t)s * NH + hh] + ern;
            v = v > 0.f ? v : SLOPE * v;
            float w = __expf(v);
            den += w;
            const unsigned short* zr = &zu[(size_t)s * HD + c0];
            bf16x8 z0 = *(const bf16x8*)&zr[0];
            bf16x8 z1 = *(const bf16x8*)&zr[8];
#pragma unroll
            for (int j = 0; j < 8; ++j) {
                num[j]     += w * bf2f((unsigned short)z0[j]);
                num[8 + j] += w * bf2f((unsigned short)z1[j]);
            }
        }
    }

    den += __shfl_xor(den, 16);
    den += __shfl_xor(den, 32);
#pragma unroll
    for (int j = 0; j < 16; ++j) {
        num[j] += __shfl_xor(num[j], 16);
        num[j] += __shfl_xor(num[j], 32);
    }

    if (es == 0) {
        float inv = (K > 0) ? 1.0f / den : 0.f;   // deg-0 node -> out = bias
        unsigned short* op = (unsigned short*)out;
        float4 bva = *(const float4*)&bias[c0];
        float4 bvb = *(const float4*)&bias[c0 + 4];
        float4 bvc = *(const float4*)&bias[c0 + 8];
        float4 bvd = *(const float4*)&bias[c0 + 12];
        float bb[16] = {bva.x, bva.y, bva.z, bva.w, bvb.x, bvb.y, bvb.z, bvb.w,
                        bvc.x, bvc.y, bvc.z, bvc.w, bvd.x, bvd.y, bvd.z, bvd.w};
        bf16x8 o0, o1;
#pragma unroll
        for (int j = 0; j < 8; ++j) {
            float v0 = num[j] * inv + bb[j];
            float v1 = num[8 + j] * inv + bb[8 + j];
            if (do_relu) { v0 = fmaxf(v0, 0.f); v1 = fmaxf(v1, 0.f); }
            o0[j] = (short)f2bf(v0);
            o1[j] = (short)f2bf(v1);
        }
        *(bf16x8*)&op[(size_t)n * HD + c0] = o0;
        *(bf16x8*)&op[(size_t)n * HD + c0 + 8] = o1;
    }
}

// ---------------- readout ----------------

__global__ __launch_bounds__(256) void graph_sum_kernel(
    const __hip_bfloat16* __restrict__ h2, const int* __restrict__ gids,
    float* __restrict__ hg)
{
    int c = threadIdx.x;
    int n0 = blockIdx.x * 64;
    int n1 = n0 + 64;
    if (n0 >= NN) return;
    if (n1 > NN) n1 = NN;
    const unsigned short* hu = (const unsigned short*)h2;
    float acc = 0.f;
    int cur = gids[n0];
    for (int n = n0; n < n1; ++n) {
        int g = gids[n];
        if (g != cur) {
            atomicAdd(&hg[cur * HD + c], acc);
            acc = 0.f;
            cur = g;
        }
        acc += bf2f(hu[(size_t)n * HD + c]);
    }
    atomicAdd(&hg[cur * HD + c], acc);
}

__global__ void classifier_kernel(const float* __restrict__ hg, const float* __restrict__ perm,
                                  const float* __restrict__ Wc, const float* __restrict__ bc,
                                  const int* __restrict__ gids, float* __restrict__ out) {
    int g = blockIdx.x;
    int c = threadIdx.x;
    if (c >= NC) return;
    int lo = 0, hi = NN;
    while (lo < hi) { int mid = (lo + hi) >> 1; if (gids[mid] < g) lo = mid + 1; else hi = mid; }
    int s0 = lo;
    lo = 0; hi = NN;
    while (lo < hi) { int mid = (lo + hi) >> 1; if (gids[mid] < g + 1) lo = mid + 1; else hi = mid; }
    float cnt = fmaxf((float)(lo - s0), 1.0f);
    float inv = 1.0f / cnt;
    float sg = 0.f;
    for (int k = 0; k < HD; ++k) sg += hg[g * HD + k] * Wc[k * NC + c];
    float s = bc[c] + sg * inv;
    for (int k = 0; k < NPERM; ++k) s += perm[g * NPERM + k] * Wc[(HD + k) * NC + c];
    out[g * NC + c] = s;
}

// ---------------- launch ----------------

extern "C" void kernel_launch(void* const* d_in, const int* in_sizes, int n_in,
                              void* d_out, int out_size, void* d_ws, size_t ws_size,
                              hipStream_t stream) {
    const float* h    = (const float*)d_in[0];
    const float* perm = (const float*)d_in[1];
    const float* W1   = (const float*)d_in[2];
    const float* al1  = (const float*)d_in[3];
    const float* ar1  = (const float*)d_in[4];
    const float* b1   = (const float*)d_in[5];
    const float* W2   = (const float*)d_in[6];
    const float* al2  = (const float*)d_in[7];
    const float* ar2  = (const float*)d_in[8];
    const float* b2   = (const float*)d_in[9];
    const float* Wc   = (const float*)d_in[10];
    const float* bc   = (const float*)d_in[11];
    const int* src    = (const int*)d_in[12];
    const int* dst    = (const int*)d_in[13];
    const int* gids   = (const int*)d_in[14];
    float* out = (float*)d_out;

    __hip_bfloat16* zb  = (__hip_bfloat16*)d_ws;                  // N*256
    __hip_bfloat16* h1b = zb + (size_t)NN * HD;                   // N*256
    __hip_bfloat16* Wt1 = h1b + (size_t)NN * HD;                  // 256*128
    __hip_bfloat16* Wt2 = Wt1 + (size_t)HD * INDIM;               // 256*256
    float* el = (float*)(Wt2 + (size_t)HD * HD);                  // N*8
    float* er = el + (size_t)NN * NH;                             // N*8
    float* hg = er + (size_t)NN * NH;                             // B*256
    int* counts = (int*)(hg + NB_G * HD);                         // N
    int* bucket = counts + NN;                                    // N*BCAP (12.8 MB)

    int nblocks_e = (NE + 255) / 256;   // 1954 scatter blocks
    int gemm_blocks = (NN + 63) / 64;   // 782
    int wave_node_blocks = (NN * 64 + 255) / 256;

    // prep: zero counts + transpose weights + zero hg
    prep_kernel<<<NB_CNT + INDIM + HD, 256, 0, stream>>>(counts, W1, W2, Wt1, Wt2, hg);

    // layer-1 gemm (K=128, fp32 input) with fused bucket scatter
    gemm_mfma_kernel<INDIM, 1><<<gemm_blocks + nblocks_e, 256, 0, stream>>>(
        h, Wt1, al1, ar1, zb, el, er, NN,
        gemm_blocks, dst, src, counts, bucket, NE);
    agg_kernel<<<wave_node_blocks, 256, 0, stream>>>(zb, el, er, b1, counts, bucket, h1b, NN, 1);
    // layer 2 (K=256, bf16 input -> single-shot global_load_lds staging)
    gemm_mfma_kernel<HD, 0><<<gemm_blocks, 256, 0, stream>>>(
        h1b, Wt2, al2, ar2, zb, el, er, NN,
        gemm_blocks, nullptr, nullptr, nullptr, nullptr, 0);
    agg_kernel<<<wave_node_blocks, 256, 0, stream>>>(zb, el, er, b2, counts, bucket, h1b, NN, 0);

    // readout
    graph_sum_kernel<<<(NN + 63) / 64, 256, 0, stream>>>(h1b, gids, hg);
    classifier_kernel<<<NB_G, 64, 0, stream>>>(hg, perm, Wc, bc, gids, out);
}

// Round 22
// 209.328 us; speedup vs baseline: 1.0588x; 1.0102x over previous
//
#include <hip/hip_runtime.h>
#include <hip/hip_bf16.h>

#define NN 50000
#define NE 500000
#define INDIM 128
#define NH 8
#define DH 32
#define HD 256
#define NPERM 100
#define NB_G 64
#define NC 10
#define SLOPE 0.2f
#define BCAP 64   // bucket capacity per node; Poisson(10) max over 50K nodes ~32, 2x margin

typedef short bf16x8 __attribute__((ext_vector_type(8)));
typedef float f32x4 __attribute__((ext_vector_type(4)));

__device__ inline float bf2f(unsigned short u) {
    union { unsigned int i; float f; } x; x.i = ((unsigned int)u) << 16; return x.f;
}
__device__ inline unsigned short f2bf(float f) {
    __hip_bfloat16 h = __float2bfloat16(f);
    return *reinterpret_cast<unsigned short*>(&h);
}

// ---------------- prep: zero counts + weight transpose + hg zero ----------------

#define NB_CNT ((NN + 255) / 256)   // 196

__global__ __launch_bounds__(256) void prep_kernel(
    int* __restrict__ counts,
    const float* __restrict__ W1, const float* __restrict__ W2,
    __hip_bfloat16* __restrict__ Wt1, __hip_bfloat16* __restrict__ Wt2,
    float* __restrict__ hg)
{
    int b = blockIdx.x;
    int c = threadIdx.x;
    if (b < NB_CNT) {
        int i = b * 256 + c;
        if (i < NN) counts[i] = 0;
    } else {
        int bb = b - NB_CNT;   // 0..383
        if (bb < INDIM) {
            Wt1[(size_t)c * INDIM + bb] = __float2bfloat16(W1[(size_t)bb * HD + c]);
        } else {
            int k = bb - INDIM;
            Wt2[(size_t)c * HD + k] = __float2bfloat16(W2[(size_t)k * HD + c]);
        }
        if (bb < NB_G) hg[bb * HD + c] = 0.f;
    }
}

// ---------------- MFMA GEMM: 64 rows x 256 cols, 256 thr / 4 waves ----------------
// R21 theory: B-operand flat loads (per-lane col stride 512B) split into 64 L2 requests
// per instruction -> request-rate bound (all pipes idle, time invariant to structure).
// Fix: stage B through LDS in 32-k tiles via global_load_lds (4 threads per 64B line =
// 16 requests/instr), MFMA reads B from LDS with lg^(col&3) swizzle (~4-way, 1.6x).
// A: whole 64 x K panel in LDS (R17 proven staging). z/el/er: direct stores (R14 form).
// Blocks >= gemm_nblocks run the edge->bucket scatter (independent; early return, no barrier).

template<int KVAL, int IS_F32>
__global__ __launch_bounds__(256) void gemm_mfma_kernel(
    const void* __restrict__ Xv, const __hip_bfloat16* __restrict__ Wt,
    const float* __restrict__ al, const float* __restrict__ ar,
    __hip_bfloat16* __restrict__ zb, float* __restrict__ el, float* __restrict__ er,
    int nrows, int gemm_nblocks,
    const int* __restrict__ dstv, const int* __restrict__ srcv,
    int* __restrict__ counts, int* __restrict__ bucket, int ne)
{
    __shared__ __attribute__((aligned(16))) unsigned short Xs[64 * KVAL];   // 16/32 KB
    __shared__ __attribute__((aligned(16))) unsigned short Ws[256 * 32];    // 16 KB B tile
    int t = threadIdx.x;

    if ((int)blockIdx.x >= gemm_nblocks) {
        int e = ((int)blockIdx.x - gemm_nblocks) * 256 + t;
        if (e < ne) {
            int d = dstv[e];
            int p = atomicAdd(&counts[d], 1);
            if (p < BCAP) bucket[(size_t)d * BCAP + p] = srcv[e];
        }
        return;
    }

    int l = t & 63;
    int wc = t >> 6;        // 0..3 -> cols [wc*64, wc*64+64)
    int nb = blockIdx.x * 64;
    int wcb = wc * 64;
    int lg = l >> 4;
    int lr = l & 15;

    const short* Wt16 = (const short*)Wt;
    constexpr int NSLOT = KVAL / 8;       // 16B slots per A row (16 or 32)
    constexpr int NKK = KVAL / 32;        // k-tiles (4 or 8)

    // ---- stage entire A panel ----
    if (IS_F32) {
        const float* Xf = (const float*)Xv;
        int row = t >> 2;
        int gr = nb + row;
#pragma unroll
        for (int i = 0; i < NSLOT / 4; ++i) {
            int j = (t & 3) + 4 * i;
            bf16x8 xv = {0, 0, 0, 0, 0, 0, 0, 0};
            if (gr < nrows) {
                const float* p = &Xf[(size_t)gr * KVAL + j * 8];
                float4 xa = *(const float4*)&p[0];
                float4 xb = *(const float4*)&p[4];
                xv[0] = (short)f2bf(xa.x); xv[1] = (short)f2bf(xa.y);
                xv[2] = (short)f2bf(xa.z); xv[3] = (short)f2bf(xa.w);
                xv[4] = (short)f2bf(xb.x); xv[5] = (short)f2bf(xb.y);
                xv[6] = (short)f2bf(xb.z); xv[7] = (short)f2bf(xb.w);
            }
            *(bf16x8*)&Xs[row * KVAL + ((j ^ (row & 7)) * 8)] = xv;
        }
    } else {
        const short* X16 = (const short*)Xv;
#pragma unroll
        for (int i = 0; i < (64 * NSLOT) / 256; ++i) {
            int c = t + i * 256;
            int row = c / NSLOT;
            int p = c % NSLOT;
            int q = p ^ (row & 7);
            const short* ga = &X16[(size_t)(nb + row) * KVAL + q * 8];
            __builtin_amdgcn_global_load_lds(
                (const __attribute__((address_space(1))) void*)ga,
                (__attribute__((address_space(3))) void*)((char*)Xs + (size_t)c * 16), 16, 0, 0);
        }
    }

    f32x4 acc[4][4];
#pragma unroll
    for (int rb = 0; rb < 4; ++rb)
#pragma unroll
        for (int cf = 0; cf < 4; ++cf) acc[rb][cf] = (f32x4){0.f, 0.f, 0.f, 0.f};

    // ---- K loop: stage B tile (256 cols x 32 k) into LDS, then pure-LDS MFMA ----
#pragma unroll
    for (int kk = 0; kk < NKK; ++kk) {
        if (kk > 0) __syncthreads();   // all waves done reading previous B tile
        // B tile staging: 1024 chunks of 16B; chunk = col*4 + p; physical p holds
        // logical seg p^(col&3) (pre-swizzled global source, linear LDS dest).
#pragma unroll
        for (int i = 0; i < 4; ++i) {
            int chunk = t + i * 256;
            int col = chunk >> 2;
            int p = chunk & 3;
            int q = p ^ (col & 3);
            const short* ga = &Wt16[(size_t)col * KVAL + kk * 32 + q * 8];
            __builtin_amdgcn_global_load_lds(
                (const __attribute__((address_space(1))) void*)ga,
                (__attribute__((address_space(3))) void*)((char*)Ws + (size_t)chunk * 16), 16, 0, 0);
        }
        __syncthreads();   // B tile ready (kk==0: also covers A panel)

        bf16x8 b[4], a[4];
#pragma unroll
        for (int cf = 0; cf < 4; ++cf) {
            int col = wcb + cf * 16 + lr;
            b[cf] = *(const bf16x8*)&Ws[col * 32 + ((lg ^ (col & 3)) * 8)];
        }
#pragma unroll
        for (int rb = 0; rb < 4; ++rb) {
            int row = rb * 16 + lr;
            int slot = (kk * 4 + lg) ^ (row & 7);
            a[rb] = *(const bf16x8*)&Xs[row * KVAL + slot * 8];
        }
#pragma unroll
        for (int rb = 0; rb < 4; ++rb)
#pragma unroll
            for (int cf = 0; cf < 4; ++cf)
                acc[rb][cf] = __builtin_amdgcn_mfma_f32_16x16x32_bf16(a[rb], b[cf], acc[rb][cf], 0, 0, 0);
    }

    // ---- epilogue: direct stores (R14/R19 form) ----
    float al_c[4], ar_c[4];
#pragma unroll
    for (int cf = 0; cf < 4; ++cf) {
        al_c[cf] = al[wcb + cf * 16 + lr];
        ar_c[cf] = ar[wcb + cf * 16 + lr];
    }

    unsigned short* zu = (unsigned short*)zb;
#pragma unroll
    for (int rb = 0; rb < 4; ++rb) {
        int rbase = nb + rb * 16 + lg * 4;
#pragma unroll
        for (int j = 0; j < 4; ++j) {
            int r = rbase + j;
            if (r < nrows) {
#pragma unroll
                for (int cf = 0; cf < 4; ++cf)
                    zu[(size_t)r * HD + wcb + cf * 16 + lr] = f2bf(acc[rb][cf][j]);
            }
        }
        float p0[4], p1[4], q0[4], q1[4];
#pragma unroll
        for (int j = 0; j < 4; ++j) {
            p0[j] = acc[rb][0][j] * al_c[0] + acc[rb][1][j] * al_c[1];
            p1[j] = acc[rb][2][j] * al_c[2] + acc[rb][3][j] * al_c[3];
            q0[j] = acc[rb][0][j] * ar_c[0] + acc[rb][1][j] * ar_c[1];
            q1[j] = acc[rb][2][j] * ar_c[2] + acc[rb][3][j] * ar_c[3];
        }
#pragma unroll
        for (int m = 1; m < 16; m <<= 1) {
#pragma unroll
            for (int j = 0; j < 4; ++j) {
                p0[j] += __shfl_xor(p0[j], m);
                p1[j] += __shfl_xor(p1[j], m);
                q0[j] += __shfl_xor(q0[j], m);
                q1[j] += __shfl_xor(q1[j], m);
            }
        }
        if (lr == 0) {
#pragma unroll
            for (int j = 0; j < 4; ++j) {
                int r = rbase + j;
                if (r < nrows) {
                    el[(size_t)r * NH + 2 * wc]     = p0[j];
                    el[(size_t)r * NH + 2 * wc + 1] = p1[j];
                    er[(size_t)r * NH + 2 * wc]     = q0[j];
                    er[(size_t)r * NH + 2 * wc + 1] = q1[j];
                }
            }
        }
    }
}

// ---------------- per-dst-node attention aggregate (R9 structure = proven floor) ----------------

__global__ __launch_bounds__(256) void agg_kernel(
    const __hip_bfloat16* __restrict__ zb, const float* __restrict__ el, const float* __restrict__ er,
    const float* __restrict__ bias, const int* __restrict__ counts,
    const int* __restrict__ bucket, __hip_bfloat16* __restrict__ out, int nrows, int do_relu)
{
    int wid = (blockIdx.x * 256 + threadIdx.x) >> 6;
    int l = threadIdx.x & 63;
    if (wid >= nrows) return;   // wave-uniform
    int n = wid;
    int K = counts[n];
    if (K > BCAP) K = BCAP;
    const int* srcs = &bucket[(size_t)n * BCAP];
    const unsigned short* zu = (const unsigned short*)zb;

    int es = l >> 4;   // edge slot 0..3
    int li = l & 15;   // channel group: c0 = li*16
    int hh = li >> 1;  // head
    float ern = er[(size_t)n * NH + hh];
    int c0 = li * 16;

    float num[16];
#pragma unroll
    for (int j = 0; j < 16; ++j) num[j] = 0.f;
    float den = 0.f;

    for (int kb = 0; kb < K; kb += 4) {
        int k = kb + es;
        if (k < K) {
            int s = srcs[k];
            float v = el[(size_t)s * NH + hh] + ern;
            v = v > 0.f ? v : SLOPE * v;
            float w = __expf(v);
            den += w;
            const unsigned short* zr = &zu[(size_t)s * HD + c0];
            bf16x8 z0 = *(const bf16x8*)&zr[0];
            bf16x8 z1 = *(const bf16x8*)&zr[8];
#pragma unroll
            for (int j = 0; j < 8; ++j) {
                num[j]     += w * bf2f((unsigned short)z0[j]);
                num[8 + j] += w * bf2f((unsigned short)z1[j]);
            }
        }
    }

    den += __shfl_xor(den, 16);
    den += __shfl_xor(den, 32);
#pragma unroll
    for (int j = 0; j < 16; ++j) {
        num[j] += __shfl_xor(num[j], 16);
        num[j] += __shfl_xor(num[j], 32);
    }

    if (es == 0) {
        float inv = (K > 0) ? 1.0f / den : 0.f;   // deg-0 node -> out = bias
        unsigned short* op = (unsigned short*)out;
        float4 bva = *(const float4*)&bias[c0];
        float4 bvb = *(const float4*)&bias[c0 + 4];
        float4 bvc = *(const float4*)&bias[c0 + 8];
        float4 bvd = *(const float4*)&bias[c0 + 12];
        float bb[16] = {bva.x, bva.y, bva.z, bva.w, bvb.x, bvb.y, bvb.z, bvb.w,
                        bvc.x, bvc.y, bvc.z, bvc.w, bvd.x, bvd.y, bvd.z, bvd.w};
        bf16x8 o0, o1;
#pragma unroll
        for (int j = 0; j < 8; ++j) {
            float v0 = num[j] * inv + bb[j];
            float v1 = num[8 + j] * inv + bb[8 + j];
            if (do_relu) { v0 = fmaxf(v0, 0.f); v1 = fmaxf(v1, 0.f); }
            o0[j] = (short)f2bf(v0);
            o1[j] = (short)f2bf(v1);
        }
        *(bf16x8*)&op[(size_t)n * HD + c0] = o0;
        *(bf16x8*)&op[(size_t)n * HD + c0 + 8] = o1;
    }
}

// ---------------- readout ----------------

__global__ __launch_bounds__(256) void graph_sum_kernel(
    const __hip_bfloat16* __restrict__ h2, const int* __restrict__ gids,
    float* __restrict__ hg)
{
    int c = threadIdx.x;
    int n0 = blockIdx.x * 64;
    int n1 = n0 + 64;
    if (n0 >= NN) return;
    if (n1 > NN) n1 = NN;
    const unsigned short* hu = (const unsigned short*)h2;
    float acc = 0.f;
    int cur = gids[n0];
    for (int n = n0; n < n1; ++n) {
        int g = gids[n];
        if (g != cur) {
            atomicAdd(&hg[cur * HD + c], acc);
            acc = 0.f;
            cur = g;
        }
        acc += bf2f(hu[(size_t)n * HD + c]);
    }
    atomicAdd(&hg[cur * HD + c], acc);
}

__global__ void classifier_kernel(const float* __restrict__ hg, const float* __restrict__ perm,
                                  const float* __restrict__ Wc, const float* __restrict__ bc,
                                  const int* __restrict__ gids, float* __restrict__ out) {
    int g = blockIdx.x;
    int c = threadIdx.x;
    if (c >= NC) return;
    int lo = 0, hi = NN;
    while (lo < hi) { int mid = (lo + hi) >> 1; if (gids[mid] < g) lo = mid + 1; else hi = mid; }
    int s0 = lo;
    lo = 0; hi = NN;
    while (lo < hi) { int mid = (lo + hi) >> 1; if (gids[mid] < g + 1) lo = mid + 1; else hi = mid; }
    float cnt = fmaxf((float)(lo - s0), 1.0f);
    float inv = 1.0f / cnt;
    float sg = 0.f;
    for (int k = 0; k < HD; ++k) sg += hg[g * HD + k] * Wc[k * NC + c];
    float s = bc[c] + sg * inv;
    for (int k = 0; k < NPERM; ++k) s += perm[g * NPERM + k] * Wc[(HD + k) * NC + c];
    out[g * NC + c] = s;
}

// ---------------- launch ----------------

extern "C" void kernel_launch(void* const* d_in, const int* in_sizes, int n_in,
                              void* d_out, int out_size, void* d_ws, size_t ws_size,
                              hipStream_t stream) {
    const float* h    = (const float*)d_in[0];
    const float* perm = (const float*)d_in[1];
    const float* W1   = (const float*)d_in[2];
    const float* al1  = (const float*)d_in[3];
    const float* ar1  = (const float*)d_in[4];
    const float* b1   = (const float*)d_in[5];
    const float* W2   = (const float*)d_in[6];
    const float* al2  = (const float*)d_in[7];
    const float* ar2  = (const float*)d_in[8];
    const float* b2   = (const float*)d_in[9];
    const float* Wc   = (const float*)d_in[10];
    const float* bc   = (const float*)d_in[11];
    const int* src    = (const int*)d_in[12];
    const int* dst    = (const int*)d_in[13];
    const int* gids   = (const int*)d_in[14];
    float* out = (float*)d_out;

    __hip_bfloat16* zb  = (__hip_bfloat16*)d_ws;                  // N*256
    __hip_bfloat16* h1b = zb + (size_t)NN * HD;                   // N*256
    __hip_bfloat16* Wt1 = h1b + (size_t)NN * HD;                  // 256*128
    __hip_bfloat16* Wt2 = Wt1 + (size_t)HD * INDIM;               // 256*256
    float* el = (float*)(Wt2 + (size_t)HD * HD);                  // N*8
    float* er = el + (size_t)NN * NH;                             // N*8
    float* hg = er + (size_t)NN * NH;                             // B*256
    int* counts = (int*)(hg + NB_G * HD);                         // N
    int* bucket = counts + NN;                                    // N*BCAP (12.8 MB)

    int nblocks_e = (NE + 255) / 256;   // 1954 scatter blocks
    int gemm_blocks = (NN + 63) / 64;   // 782
    int wave_node_blocks = (NN * 64 + 255) / 256;

    // prep: zero counts + transpose weights + zero hg
    prep_kernel<<<NB_CNT + INDIM + HD, 256, 0, stream>>>(counts, W1, W2, Wt1, Wt2, hg);

    // layer-1 gemm (K=128, fp32 input) with fused bucket scatter
    gemm_mfma_kernel<INDIM, 1><<<gemm_blocks + nblocks_e, 256, 0, stream>>>(
        h, Wt1, al1, ar1, zb, el, er, NN,
        gemm_blocks, dst, src, counts, bucket, NE);
    agg_kernel<<<wave_node_blocks, 256, 0, stream>>>(zb, el, er, b1, counts, bucket, h1b, NN, 1);
    // layer 2 (K=256, bf16 input)
    gemm_mfma_kernel<HD, 0><<<gemm_blocks, 256, 0, stream>>>(
        h1b, Wt2, al2, ar2, zb, el, er, NN,
        gemm_blocks, nullptr, nullptr, nullptr, nullptr, 0);
    agg_kernel<<<wave_node_blocks, 256, 0, stream>>>(zb, el, er, b2, counts, bucket, h1b, NN, 0);

    // readout
    graph_sum_kernel<<<(NN + 63) / 64, 256, 0, stream>>>(h1b, gids, hg);
    classifier_kernel<<<NB_G, 64, 0, stream>>>(hg, perm, Wc, bc, gids, out);
}

// Round 23
// 206.540 us; speedup vs baseline: 1.0731x; 1.0135x over previous
//
#include <hip/hip_runtime.h>
#include <hip/hip_bf16.h>

#define NN 50000
#define NE 500000
#define INDIM 128
#define NH 8
#define DH 32
#define HD 256
#define NPERM 100
#define NB_G 64
#define NC 10
#define SLOPE 0.2f
#define BCAP 64   // bucket capacity per node; Poisson(10) max over 50K nodes ~32, 2x margin

typedef short bf16x8 __attribute__((ext_vector_type(8)));
typedef float f32x4 __attribute__((ext_vector_type(4)));

__device__ inline float bf2f(unsigned short u) {
    union { unsigned int i; float f; } x; x.i = ((unsigned int)u) << 16; return x.f;
}
__device__ inline unsigned short f2bf(float f) {
    __hip_bfloat16 h = __float2bfloat16(f);
    return *reinterpret_cast<unsigned short*>(&h);
}

// ---------------- prep: zero counts + weight transpose + hg zero ----------------

#define NB_CNT ((NN + 255) / 256)   // 196

__global__ __launch_bounds__(256) void prep_kernel(
    int* __restrict__ counts,
    const float* __restrict__ W1, const float* __restrict__ W2,
    __hip_bfloat16* __restrict__ Wt1, __hip_bfloat16* __restrict__ Wt2,
    float* __restrict__ hg)
{
    int b = blockIdx.x;
    int c = threadIdx.x;
    if (b < NB_CNT) {
        int i = b * 256 + c;
        if (i < NN) counts[i] = 0;
    } else {
        int bb = b - NB_CNT;   // 0..383
        if (bb < INDIM) {
            Wt1[(size_t)c * INDIM + bb] = __float2bfloat16(W1[(size_t)bb * HD + c]);
        } else {
            int k = bb - INDIM;
            Wt2[(size_t)c * HD + k] = __float2bfloat16(W2[(size_t)k * HD + c]);
        }
        if (bb < NB_G) hg[bb * HD + c] = 0.f;
    }
}

// ---------------- MFMA GEMM: 128 rows x 256 cols, 512 thr / 8 waves, whole-panel LDS ----------------
// R23 experiment: fixed-cost-per-block model. 391 blocks (~1.5 rounds/CU, was 782/~3)
// and each block loads B once per 128 rows (half the B traffic). Single barrier
// (R17 structure). Wave (wr,wc): wr in 0..1 (row half), wc in 0..3 (64-col strip).
// A from LDS (slot p = logical q ^ (row&7)); B flat from L2-resident Wt.
// z/el/er: direct stores. Blocks >= gemm_nblocks run the bucket scatter (512 thr).

template<int KVAL, int IS_F32>
__global__ __launch_bounds__(512) void gemm_mfma_kernel(
    const void* __restrict__ Xv, const __hip_bfloat16* __restrict__ Wt,
    const float* __restrict__ al, const float* __restrict__ ar,
    __hip_bfloat16* __restrict__ zb, float* __restrict__ el, float* __restrict__ er,
    int nrows, int gemm_nblocks,
    const int* __restrict__ dstv, const int* __restrict__ srcv,
    int* __restrict__ counts, int* __restrict__ bucket, int ne)
{
    __shared__ __attribute__((aligned(16))) unsigned short Xs[128 * KVAL];   // 32/64 KB
    int t = threadIdx.x;

    if ((int)blockIdx.x >= gemm_nblocks) {
        // fused bucket scatter (block-uniform; never reaches the barrier)
        int e = ((int)blockIdx.x - gemm_nblocks) * 512 + t;
        if (e < ne) {
            int d = dstv[e];
            int p = atomicAdd(&counts[d], 1);
            if (p < BCAP) bucket[(size_t)d * BCAP + p] = srcv[e];
        }
        return;
    }

    int l = t & 63;
    int wv = t >> 6;        // 0..7
    int wr = wv >> 2;       // 0..1 -> rows [wr*64, wr*64+64)
    int wc = wv & 3;        // 0..3 -> cols [wc*64, wc*64+64)
    int nb = blockIdx.x * 128;
    int wcb = wc * 64;
    int lg = l >> 4;
    int lr = l & 15;

    const short* Wt16 = (const short*)Wt;
    constexpr int NSLOT = KVAL / 8;       // 16B slots per A row (16 or 32)
    constexpr int NKK = KVAL / 32;        // MFMA k-steps (4 or 8)

    // ---- stage entire 128 x K A panel (single shot) ----
    if (IS_F32) {
        // fp32 -> bf16 register staging: thread t owns row t>>2 (0..127), slots (t&3)+4i
        const float* Xf = (const float*)Xv;
        int row = t >> 2;
        int gr = nb + row;
#pragma unroll
        for (int i = 0; i < NSLOT / 4; ++i) {
            int j = (t & 3) + 4 * i;
            bf16x8 xv = {0, 0, 0, 0, 0, 0, 0, 0};
            if (gr < nrows) {
                const float* p = &Xf[(size_t)gr * KVAL + j * 8];
                float4 xa = *(const float4*)&p[0];
                float4 xb = *(const float4*)&p[4];
                xv[0] = (short)f2bf(xa.x); xv[1] = (short)f2bf(xa.y);
                xv[2] = (short)f2bf(xa.z); xv[3] = (short)f2bf(xa.w);
                xv[4] = (short)f2bf(xb.x); xv[5] = (short)f2bf(xb.y);
                xv[6] = (short)f2bf(xb.z); xv[7] = (short)f2bf(xb.w);
            }
            *(bf16x8*)&Xs[row * KVAL + ((j ^ (row & 7)) * 8)] = xv;
        }
    } else {
        // bf16: global_load_lds, linear LDS dest, pre-swizzled global source
        const short* X16 = (const short*)Xv;
#pragma unroll
        for (int i = 0; i < (128 * NSLOT) / 512; ++i) {
            int c = t + i * 512;
            int row = c / NSLOT;
            int p = c % NSLOT;
            int q = p ^ (row & 7);
            const short* ga = &X16[(size_t)(nb + row) * KVAL + q * 8];
            __builtin_amdgcn_global_load_lds(
                (const __attribute__((address_space(1))) void*)ga,
                (__attribute__((address_space(3))) void*)((char*)Xs + (size_t)c * 16), 16, 0, 0);
        }
    }
    __syncthreads();   // the single barrier

    // ---- MFMA loop, no barriers ----
    f32x4 acc[4][4];
#pragma unroll
    for (int rb = 0; rb < 4; ++rb)
#pragma unroll
        for (int cf = 0; cf < 4; ++cf) acc[rb][cf] = (f32x4){0.f, 0.f, 0.f, 0.f};

#pragma unroll
    for (int kk = 0; kk < NKK; ++kk) {
        bf16x8 b[4], a[4];
#pragma unroll
        for (int cf = 0; cf < 4; ++cf) {
            int col = wcb + cf * 16 + lr;
            b[cf] = *(const bf16x8*)&Wt16[(size_t)col * KVAL + kk * 32 + lg * 8];
        }
#pragma unroll
        for (int rb = 0; rb < 4; ++rb) {
            int row = wr * 64 + rb * 16 + lr;
            int slot = (kk * 4 + lg) ^ (row & 7);
            a[rb] = *(const bf16x8*)&Xs[row * KVAL + slot * 8];
        }
#pragma unroll
        for (int rb = 0; rb < 4; ++rb)
#pragma unroll
            for (int cf = 0; cf < 4; ++cf)
                acc[rb][cf] = __builtin_amdgcn_mfma_f32_16x16x32_bf16(a[rb], b[cf], acc[rb][cf], 0, 0, 0);
    }

    // ---- epilogue: direct stores ----
    float al_c[4], ar_c[4];
#pragma unroll
    for (int cf = 0; cf < 4; ++cf) {
        al_c[cf] = al[wcb + cf * 16 + lr];
        ar_c[cf] = ar[wcb + cf * 16 + lr];
    }

    unsigned short* zu = (unsigned short*)zb;
#pragma unroll
    for (int rb = 0; rb < 4; ++rb) {
        int rbase = nb + wr * 64 + rb * 16 + lg * 4;
#pragma unroll
        for (int j = 0; j < 4; ++j) {
            int r = rbase + j;
            if (r < nrows) {
#pragma unroll
                for (int cf = 0; cf < 4; ++cf)
                    zu[(size_t)r * HD + wcb + cf * 16 + lr] = f2bf(acc[rb][cf][j]);
            }
        }
        float p0[4], p1[4], q0[4], q1[4];
#pragma unroll
        for (int j = 0; j < 4; ++j) {
            p0[j] = acc[rb][0][j] * al_c[0] + acc[rb][1][j] * al_c[1];
            p1[j] = acc[rb][2][j] * al_c[2] + acc[rb][3][j] * al_c[3];
            q0[j] = acc[rb][0][j] * ar_c[0] + acc[rb][1][j] * ar_c[1];
            q1[j] = acc[rb][2][j] * ar_c[2] + acc[rb][3][j] * ar_c[3];
        }
#pragma unroll
        for (int m = 1; m < 16; m <<= 1) {
#pragma unroll
            for (int j = 0; j < 4; ++j) {
                p0[j] += __shfl_xor(p0[j], m);
                p1[j] += __shfl_xor(p1[j], m);
                q0[j] += __shfl_xor(q0[j], m);
                q1[j] += __shfl_xor(q1[j], m);
            }
        }
        if (lr == 0) {
#pragma unroll
            for (int j = 0; j < 4; ++j) {
                int r = rbase + j;
                if (r < nrows) {
                    el[(size_t)r * NH + 2 * wc]     = p0[j];
                    el[(size_t)r * NH + 2 * wc + 1] = p1[j];
                    er[(size_t)r * NH + 2 * wc]     = q0[j];
                    er[(size_t)r * NH + 2 * wc + 1] = q1[j];
                }
            }
        }
    }
}

// ---------------- per-dst-node attention aggregate (R9 structure = proven floor) ----------------

__global__ __launch_bounds__(256) void agg_kernel(
    const __hip_bfloat16* __restrict__ zb, const float* __restrict__ el, const float* __restrict__ er,
    const float* __restrict__ bias, const int* __restrict__ counts,
    const int* __restrict__ bucket, __hip_bfloat16* __restrict__ out, int nrows, int do_relu)
{
    int wid = (blockIdx.x * 256 + threadIdx.x) >> 6;
    int l = threadIdx.x & 63;
    if (wid >= nrows) return;   // wave-uniform
    int n = wid;
    int K = counts[n];
    if (K > BCAP) K = BCAP;
    const int* srcs = &bucket[(size_t)n * BCAP];
    const unsigned short* zu = (const unsigned short*)zb;

    int es = l >> 4;   // edge slot 0..3
    int li = l & 15;   // channel group: c0 = li*16
    int hh = li >> 1;  // head
    float ern = er[(size_t)n * NH + hh];
    int c0 = li * 16;

    float num[16];
#pragma unroll
    for (int j = 0; j < 16; ++j) num[j] = 0.f;
    float den = 0.f;

    for (int kb = 0; kb < K; kb += 4) {
        int k = kb + es;
        if (k < K) {
            int s = srcs[k];
            float v = el[(size_t)s * NH + hh] + ern;
            v = v > 0.f ? v : SLOPE * v;
            float w = __expf(v);
            den += w;
            const unsigned short* zr = &zu[(size_t)s * HD + c0];
            bf16x8 z0 = *(const bf16x8*)&zr[0];
            bf16x8 z1 = *(const bf16x8*)&zr[8];
#pragma unroll
            for (int j = 0; j < 8; ++j) {
                num[j]     += w * bf2f((unsigned short)z0[j]);
                num[8 + j] += w * bf2f((unsigned short)z1[j]);
            }
        }
    }

    den += __shfl_xor(den, 16);
    den += __shfl_xor(den, 32);
#pragma unroll
    for (int j = 0; j < 16; ++j) {
        num[j] += __shfl_xor(num[j], 16);
        num[j] += __shfl_xor(num[j], 32);
    }

    if (es == 0) {
        float inv = (K > 0) ? 1.0f / den : 0.f;   // deg-0 node -> out = bias
        unsigned short* op = (unsigned short*)out;
        float4 bva = *(const float4*)&bias[c0];
        float4 bvb = *(const float4*)&bias[c0 + 4];
        float4 bvc = *(const float4*)&bias[c0 + 8];
        float4 bvd = *(const float4*)&bias[c0 + 12];
        float bb[16] = {bva.x, bva.y, bva.z, bva.w, bvb.x, bvb.y, bvb.z, bvb.w,
                        bvc.x, bvc.y, bvc.z, bvc.w, bvd.x, bvd.y, bvd.z, bvd.w};
        bf16x8 o0, o1;
#pragma unroll
        for (int j = 0; j < 8; ++j) {
            float v0 = num[j] * inv + bb[j];
            float v1 = num[8 + j] * inv + bb[8 + j];
            if (do_relu) { v0 = fmaxf(v0, 0.f); v1 = fmaxf(v1, 0.f); }
            o0[j] = (short)f2bf(v0);
            o1[j] = (short)f2bf(v1);
        }
        *(bf16x8*)&op[(size_t)n * HD + c0] = o0;
        *(bf16x8*)&op[(size_t)n * HD + c0 + 8] = o1;
    }
}

// ---------------- readout ----------------

__global__ __launch_bounds__(256) void graph_sum_kernel(
    const __hip_bfloat16* __restrict__ h2, const int* __restrict__ gids,
    float* __restrict__ hg)
{
    int c = threadIdx.x;
    int n0 = blockIdx.x * 64;
    int n1 = n0 + 64;
    if (n0 >= NN) return;
    if (n1 > NN) n1 = NN;
    const unsigned short* hu = (const unsigned short*)h2;
    float acc = 0.f;
    int cur = gids[n0];
    for (int n = n0; n < n1; ++n) {
        int g = gids[n];
        if (g != cur) {
            atomicAdd(&hg[cur * HD + c], acc);
            acc = 0.f;
            cur = g;
        }
        acc += bf2f(hu[(size_t)n * HD + c]);
    }
    atomicAdd(&hg[cur * HD + c], acc);
}

__global__ void classifier_kernel(const float* __restrict__ hg, const float* __restrict__ perm,
                                  const float* __restrict__ Wc, const float* __restrict__ bc,
                                  const int* __restrict__ gids, float* __restrict__ out) {
    int g = blockIdx.x;
    int c = threadIdx.x;
    if (c >= NC) return;
    int lo = 0, hi = NN;
    while (lo < hi) { int mid = (lo + hi) >> 1; if (gids[mid] < g) lo = mid + 1; else hi = mid; }
    int s0 = lo;
    lo = 0; hi = NN;
    while (lo < hi) { int mid = (lo + hi) >> 1; if (gids[mid] < g + 1) lo = mid + 1; else hi = mid; }
    float cnt = fmaxf((float)(lo - s0), 1.0f);
    float inv = 1.0f / cnt;
    float sg = 0.f;
    for (int k = 0; k < HD; ++k) sg += hg[g * HD + k] * Wc[k * NC + c];
    float s = bc[c] + sg * inv;
    for (int k = 0; k < NPERM; ++k) s += perm[g * NPERM + k] * Wc[(HD + k) * NC + c];
    out[g * NC + c] = s;
}

// ---------------- launch ----------------

extern "C" void kernel_launch(void* const* d_in, const int* in_sizes, int n_in,
                              void* d_out, int out_size, void* d_ws, size_t ws_size,
                              hipStream_t stream) {
    const float* h    = (const float*)d_in[0];
    const float* perm = (const float*)d_in[1];
    const float* W1   = (const float*)d_in[2];
    const float* al1  = (const float*)d_in[3];
    const float* ar1  = (const float*)d_in[4];
    const float* b1   = (const float*)d_in[5];
    const float* W2   = (const float*)d_in[6];
    const float* al2  = (const float*)d_in[7];
    const float* ar2  = (const float*)d_in[8];
    const float* b2   = (const float*)d_in[9];
    const float* Wc   = (const float*)d_in[10];
    const float* bc   = (const float*)d_in[11];
    const int* src    = (const int*)d_in[12];
    const int* dst    = (const int*)d_in[13];
    const int* gids   = (const int*)d_in[14];
    float* out = (float*)d_out;

    __hip_bfloat16* zb  = (__hip_bfloat16*)d_ws;                  // N*256
    __hip_bfloat16* h1b = zb + (size_t)NN * HD;                   // N*256
    __hip_bfloat16* Wt1 = h1b + (size_t)NN * HD;                  // 256*128
    __hip_bfloat16* Wt2 = Wt1 + (size_t)HD * INDIM;               // 256*256
    float* el = (float*)(Wt2 + (size_t)HD * HD);                  // N*8
    float* er = el + (size_t)NN * NH;                             // N*8
    float* hg = er + (size_t)NN * NH;                             // B*256
    int* counts = (int*)(hg + NB_G * HD);                         // N
    int* bucket = counts + NN;                                    // N*BCAP (12.8 MB)

    int nblocks_e512 = (NE + 511) / 512;   // 977 scatter blocks
    int gemm_blocks = (NN + 127) / 128;    // 391
    int wave_node_blocks = (NN * 64 + 255) / 256;

    // prep: zero counts + transpose weights + zero hg
    prep_kernel<<<NB_CNT + INDIM + HD, 256, 0, stream>>>(counts, W1, W2, Wt1, Wt2, hg);

    // layer-1 gemm (K=128, fp32 input) with fused bucket scatter
    gemm_mfma_kernel<INDIM, 1><<<gemm_blocks + nblocks_e512, 512, 0, stream>>>(
        h, Wt1, al1, ar1, zb, el, er, NN,
        gemm_blocks, dst, src, counts, bucket, NE);
    agg_kernel<<<wave_node_blocks, 256, 0, stream>>>(zb, el, er, b1, counts, bucket, h1b, NN, 1);
    // layer 2 (K=256, bf16 input -> single-shot global_load_lds staging, 64 KB LDS)
    gemm_mfma_kernel<HD, 0><<<gemm_blocks, 512, 0, stream>>>(
        h1b, Wt2, al2, ar2, zb, el, er, NN,
        gemm_blocks, nullptr, nullptr, nullptr, nullptr, 0);
    agg_kernel<<<wave_node_blocks, 256, 0, stream>>>(zb, el, er, b2, counts, bucket, h1b, NN, 0);

    // readout
    graph_sum_kernel<<<(NN + 63) / 64, 256, 0, stream>>>(h1b, gids, hg);
    classifier_kernel<<<NB_G, 64, 0, stream>>>(hg, perm, Wc, bc, gids, out);
}

// Round 24
// 204.762 us; speedup vs baseline: 1.0824x; 1.0087x over previous
//
#include <hip/hip_runtime.h>
#include <hip/hip_bf16.h>

#define NN 50000
#define NE 500000
#define INDIM 128
#define NH 8
#define DH 32
#define HD 256
#define NPERM 100
#define NB_G 64
#define NC 10
#define SLOPE 0.2f
#define BCAP 64   // bucket capacity per node; Poisson(10) max over 50K nodes ~32, 2x margin

typedef short bf16x8 __attribute__((ext_vector_type(8)));
typedef float f32x4 __attribute__((ext_vector_type(4)));

__device__ inline float bf2f(unsigned short u) {
    union { unsigned int i; float f; } x; x.i = ((unsigned int)u) << 16; return x.f;
}
__device__ inline unsigned short f2bf(float f) {
    __hip_bfloat16 h = __float2bfloat16(f);
    return *reinterpret_cast<unsigned short*>(&h);
}

// ---------------- prep: zero counts + weight transpose + hg zero ----------------

#define NB_CNT ((NN + 255) / 256)   // 196

__global__ __launch_bounds__(256) void prep_kernel(
    int* __restrict__ counts,
    const float* __restrict__ W1, const float* __restrict__ W2,
    __hip_bfloat16* __restrict__ Wt1, __hip_bfloat16* __restrict__ Wt2,
    float* __restrict__ hg)
{
    int b = blockIdx.x;
    int c = threadIdx.x;
    if (b < NB_CNT) {
        int i = b * 256 + c;
        if (i < NN) counts[i] = 0;
    } else {
        int bb = b - NB_CNT;   // 0..383
        if (bb < INDIM) {
            Wt1[(size_t)c * INDIM + bb] = __float2bfloat16(W1[(size_t)bb * HD + c]);
        } else {
            int k = bb - INDIM;
            Wt2[(size_t)c * HD + k] = __float2bfloat16(W2[(size_t)k * HD + c]);
        }
        if (bb < NB_G) hg[bb * HD + c] = 0.f;
    }
}

// ---------------- MFMA GEMM: ROWS x 256 cols, TPB threads, whole-panel LDS, single barrier ----------------
// R23 confirmed: gemm time scales with block count (fixed per-block memory-system cost),
// not internal structure. R24 pushes layer-1 to ROWS=256 / TPB=1024 (196 blocks, <1 round/CU,
// B loaded once per 256 rows). Layer-2 stays ROWS=128 / TPB=512 (LDS-capped at 64 KB).
// Invariant: TPB/ROWS == 4 (staging index algebra identical across variants).
// Wave (wr, wc): wr = wv>>2 (64-row group), wc = wv&3 (64-col strip); acc[4][4].
// A from LDS (slot p = logical q ^ (row&7)); B flat from L2-resident Wt.
// Blocks >= gemm_nblocks run the edge->bucket scatter (early return, no barrier).

template<int KVAL, int IS_F32, int ROWS, int TPB>
__global__ __launch_bounds__(TPB) void gemm_mfma_kernel(
    const void* __restrict__ Xv, const __hip_bfloat16* __restrict__ Wt,
    const float* __restrict__ al, const float* __restrict__ ar,
    __hip_bfloat16* __restrict__ zb, float* __restrict__ el, float* __restrict__ er,
    int nrows, int gemm_nblocks,
    const int* __restrict__ dstv, const int* __restrict__ srcv,
    int* __restrict__ counts, int* __restrict__ bucket, int ne)
{
    __shared__ __attribute__((aligned(16))) unsigned short Xs[ROWS * KVAL];   // <= 64 KB
    int t = threadIdx.x;

    if ((int)blockIdx.x >= gemm_nblocks) {
        // fused bucket scatter (block-uniform; never reaches the barrier)
        int e = ((int)blockIdx.x - gemm_nblocks) * TPB + t;
        if (e < ne) {
            int d = dstv[e];
            int p = atomicAdd(&counts[d], 1);
            if (p < BCAP) bucket[(size_t)d * BCAP + p] = srcv[e];
        }
        return;
    }

    int l = t & 63;
    int wv = t >> 6;
    int wr = wv >> 2;       // 64-row group
    int wc = wv & 3;        // 64-col strip
    int nb = blockIdx.x * ROWS;
    int wcb = wc * 64;
    int lg = l >> 4;
    int lr = l & 15;

    const short* Wt16 = (const short*)Wt;
    constexpr int NSLOT = KVAL / 8;       // 16B slots per A row
    constexpr int NKK = KVAL / 32;        // MFMA k-steps

    // ---- stage entire ROWS x K A panel (single shot); TPB/ROWS == 4 ----
    if (IS_F32) {
        const float* Xf = (const float*)Xv;
        int row = t >> 2;
        int gr = nb + row;
#pragma unroll
        for (int i = 0; i < NSLOT / 4; ++i) {
            int j = (t & 3) + 4 * i;
            bf16x8 xv = {0, 0, 0, 0, 0, 0, 0, 0};
            if (gr < nrows) {
                const float* p = &Xf[(size_t)gr * KVAL + j * 8];
                float4 xa = *(const float4*)&p[0];
                float4 xb = *(const float4*)&p[4];
                xv[0] = (short)f2bf(xa.x); xv[1] = (short)f2bf(xa.y);
                xv[2] = (short)f2bf(xa.z); xv[3] = (short)f2bf(xa.w);
                xv[4] = (short)f2bf(xb.x); xv[5] = (short)f2bf(xb.y);
                xv[6] = (short)f2bf(xb.z); xv[7] = (short)f2bf(xb.w);
            }
            *(bf16x8*)&Xs[row * KVAL + ((j ^ (row & 7)) * 8)] = xv;
        }
    } else {
        const short* X16 = (const short*)Xv;
#pragma unroll
        for (int i = 0; i < (ROWS * NSLOT) / TPB; ++i) {
            int c = t + i * TPB;
            int row = c / NSLOT;
            int p = c % NSLOT;
            int q = p ^ (row & 7);
            const short* ga = &X16[(size_t)(nb + row) * KVAL + q * 8];
            __builtin_amdgcn_global_load_lds(
                (const __attribute__((address_space(1))) void*)ga,
                (__attribute__((address_space(3))) void*)((char*)Xs + (size_t)c * 16), 16, 0, 0);
        }
    }
    __syncthreads();   // the single barrier

    // ---- MFMA loop, no barriers ----
    f32x4 acc[4][4];
#pragma unroll
    for (int rb = 0; rb < 4; ++rb)
#pragma unroll
        for (int cf = 0; cf < 4; ++cf) acc[rb][cf] = (f32x4){0.f, 0.f, 0.f, 0.f};

#pragma unroll
    for (int kk = 0; kk < NKK; ++kk) {
        bf16x8 b[4], a[4];
#pragma unroll
        for (int cf = 0; cf < 4; ++cf) {
            int col = wcb + cf * 16 + lr;
            b[cf] = *(const bf16x8*)&Wt16[(size_t)col * KVAL + kk * 32 + lg * 8];
        }
#pragma unroll
        for (int rb = 0; rb < 4; ++rb) {
            int row = wr * 64 + rb * 16 + lr;
            int slot = (kk * 4 + lg) ^ (row & 7);
            a[rb] = *(const bf16x8*)&Xs[row * KVAL + slot * 8];
        }
#pragma unroll
        for (int rb = 0; rb < 4; ++rb)
#pragma unroll
            for (int cf = 0; cf < 4; ++cf)
                acc[rb][cf] = __builtin_amdgcn_mfma_f32_16x16x32_bf16(a[rb], b[cf], acc[rb][cf], 0, 0, 0);
    }

    // ---- epilogue: direct stores ----
    float al_c[4], ar_c[4];
#pragma unroll
    for (int cf = 0; cf < 4; ++cf) {
        al_c[cf] = al[wcb + cf * 16 + lr];
        ar_c[cf] = ar[wcb + cf * 16 + lr];
    }

    unsigned short* zu = (unsigned short*)zb;
#pragma unroll
    for (int rb = 0; rb < 4; ++rb) {
        int rbase = nb + wr * 64 + rb * 16 + lg * 4;
#pragma unroll
        for (int j = 0; j < 4; ++j) {
            int r = rbase + j;
            if (r < nrows) {
#pragma unroll
                for (int cf = 0; cf < 4; ++cf)
                    zu[(size_t)r * HD + wcb + cf * 16 + lr] = f2bf(acc[rb][cf][j]);
            }
        }
        float p0[4], p1[4], q0[4], q1[4];
#pragma unroll
        for (int j = 0; j < 4; ++j) {
            p0[j] = acc[rb][0][j] * al_c[0] + acc[rb][1][j] * al_c[1];
            p1[j] = acc[rb][2][j] * al_c[2] + acc[rb][3][j] * al_c[3];
            q0[j] = acc[rb][0][j] * ar_c[0] + acc[rb][1][j] * ar_c[1];
            q1[j] = acc[rb][2][j] * ar_c[2] + acc[rb][3][j] * ar_c[3];
        }
#pragma unroll
        for (int m = 1; m < 16; m <<= 1) {
#pragma unroll
            for (int j = 0; j < 4; ++j) {
                p0[j] += __shfl_xor(p0[j], m);
                p1[j] += __shfl_xor(p1[j], m);
                q0[j] += __shfl_xor(q0[j], m);
                q1[j] += __shfl_xor(q1[j], m);
            }
        }
        if (lr == 0) {
#pragma unroll
            for (int j = 0; j < 4; ++j) {
                int r = rbase + j;
                if (r < nrows) {
                    el[(size_t)r * NH + 2 * wc]     = p0[j];
                    el[(size_t)r * NH + 2 * wc + 1] = p1[j];
                    er[(size_t)r * NH + 2 * wc]     = q0[j];
                    er[(size_t)r * NH + 2 * wc + 1] = q1[j];
                }
            }
        }
    }
}

// ---------------- per-dst-node attention aggregate (R9 structure = proven floor) ----------------

__global__ __launch_bounds__(256) void agg_kernel(
    const __hip_bfloat16* __restrict__ zb, const float* __restrict__ el, const float* __restrict__ er,
    const float* __restrict__ bias, const int* __restrict__ counts,
    const int* __restrict__ bucket, __hip_bfloat16* __restrict__ out, int nrows, int do_relu)
{
    int wid = (blockIdx.x * 256 + threadIdx.x) >> 6;
    int l = threadIdx.x & 63;
    if (wid >= nrows) return;   // wave-uniform
    int n = wid;
    int K = counts[n];
    if (K > BCAP) K = BCAP;
    const int* srcs = &bucket[(size_t)n * BCAP];
    const unsigned short* zu = (const unsigned short*)zb;

    int es = l >> 4;   // edge slot 0..3
    int li = l & 15;   // channel group: c0 = li*16
    int hh = li >> 1;  // head
    float ern = er[(size_t)n * NH + hh];
    int c0 = li * 16;

    float num[16];
#pragma unroll
    for (int j = 0; j < 16; ++j) num[j] = 0.f;
    float den = 0.f;

    for (int kb = 0; kb < K; kb += 4) {
        int k = kb + es;
        if (k < K) {
            int s = srcs[k];
            float v = el[(size_t)s * NH + hh] + ern;
            v = v > 0.f ? v : SLOPE * v;
            float w = __expf(v);
            den += w;
            const unsigned short* zr = &zu[(size_t)s * HD + c0];
            bf16x8 z0 = *(const bf16x8*)&zr[0];
            bf16x8 z1 = *(const bf16x8*)&zr[8];
#pragma unroll
            for (int j = 0; j < 8; ++j) {
                num[j]     += w * bf2f((unsigned short)z0[j]);
                num[8 + j] += w * bf2f((unsigned short)z1[j]);
            }
        }
    }

    den += __shfl_xor(den, 16);
    den += __shfl_xor(den, 32);
#pragma unroll
    for (int j = 0; j < 16; ++j) {
        num[j] += __shfl_xor(num[j], 16);
        num[j] += __shfl_xor(num[j], 32);
    }

    if (es == 0) {
        float inv = (K > 0) ? 1.0f / den : 0.f;   // deg-0 node -> out = bias
        unsigned short* op = (unsigned short*)out;
        float4 bva = *(const float4*)&bias[c0];
        float4 bvb = *(const float4*)&bias[c0 + 4];
        float4 bvc = *(const float4*)&bias[c0 + 8];
        float4 bvd = *(const float4*)&bias[c0 + 12];
        float bb[16] = {bva.x, bva.y, bva.z, bva.w, bvb.x, bvb.y, bvb.z, bvb.w,
                        bvc.x, bvc.y, bvc.z, bvc.w, bvd.x, bvd.y, bvd.z, bvd.w};
        bf16x8 o0, o1;
#pragma unroll
        for (int j = 0; j < 8; ++j) {
            float v0 = num[j] * inv + bb[j];
            float v1 = num[8 + j] * inv + bb[8 + j];
            if (do_relu) { v0 = fmaxf(v0, 0.f); v1 = fmaxf(v1, 0.f); }
            o0[j] = (short)f2bf(v0);
            o1[j] = (short)f2bf(v1);
        }
        *(bf16x8*)&op[(size_t)n * HD + c0] = o0;
        *(bf16x8*)&op[(size_t)n * HD + c0 + 8] = o1;
    }
}

// ---------------- readout ----------------

__global__ __launch_bounds__(256) void graph_sum_kernel(
    const __hip_bfloat16* __restrict__ h2, const int* __restrict__ gids,
    float* __restrict__ hg)
{
    int c = threadIdx.x;
    int n0 = blockIdx.x * 64;
    int n1 = n0 + 64;
    if (n0 >= NN) return;
    if (n1 > NN) n1 = NN;
    const unsigned short* hu = (const unsigned short*)h2;
    float acc = 0.f;
    int cur = gids[n0];
    for (int n = n0; n < n1; ++n) {
        int g = gids[n];
        if (g != cur) {
            atomicAdd(&hg[cur * HD + c], acc);
            acc = 0.f;
            cur = g;
        }
        acc += bf2f(hu[(size_t)n * HD + c]);
    }
    atomicAdd(&hg[cur * HD + c], acc);
}

__global__ void classifier_kernel(const float* __restrict__ hg, const float* __restrict__ perm,
                                  const float* __restrict__ Wc, const float* __restrict__ bc,
                                  const int* __restrict__ gids, float* __restrict__ out) {
    int g = blockIdx.x;
    int c = threadIdx.x;
    if (c >= NC) return;
    int lo = 0, hi = NN;
    while (lo < hi) { int mid = (lo + hi) >> 1; if (gids[mid] < g) lo = mid + 1; else hi = mid; }
    int s0 = lo;
    lo = 0; hi = NN;
    while (lo < hi) { int mid = (lo + hi) >> 1; if (gids[mid] < g + 1) lo = mid + 1; else hi = mid; }
    float cnt = fmaxf((float)(lo - s0), 1.0f);
    float inv = 1.0f / cnt;
    float sg = 0.f;
    for (int k = 0; k < HD; ++k) sg += hg[g * HD + k] * Wc[k * NC + c];
    float s = bc[c] + sg * inv;
    for (int k = 0; k < NPERM; ++k) s += perm[g * NPERM + k] * Wc[(HD + k) * NC + c];
    out[g * NC + c] = s;
}

// ---------------- launch ----------------

extern "C" void kernel_launch(void* const* d_in, const int* in_sizes, int n_in,
                              void* d_out, int out_size, void* d_ws, size_t ws_size,
                              hipStream_t stream) {
    const float* h    = (const float*)d_in[0];
    const float* perm = (const float*)d_in[1];
    const float* W1   = (const float*)d_in[2];
    const float* al1  = (const float*)d_in[3];
    const float* ar1  = (const float*)d_in[4];
    const float* b1   = (const float*)d_in[5];
    const float* W2   = (const float*)d_in[6];
    const float* al2  = (const float*)d_in[7];
    const float* ar2  = (const float*)d_in[8];
    const float* b2   = (const float*)d_in[9];
    const float* Wc   = (const float*)d_in[10];
    const float* bc   = (const float*)d_in[11];
    const int* src    = (const int*)d_in[12];
    const int* dst    = (const int*)d_in[13];
    const int* gids   = (const int*)d_in[14];
    float* out = (float*)d_out;

    __hip_bfloat16* zb  = (__hip_bfloat16*)d_ws;                  // N*256
    __hip_bfloat16* h1b = zb + (size_t)NN * HD;                   // N*256
    __hip_bfloat16* Wt1 = h1b + (size_t)NN * HD;                  // 256*128
    __hip_bfloat16* Wt2 = Wt1 + (size_t)HD * INDIM;               // 256*256
    float* el = (float*)(Wt2 + (size_t)HD * HD);                  // N*8
    float* er = el + (size_t)NN * NH;                             // N*8
    float* hg = er + (size_t)NN * NH;                             // B*256
    int* counts = (int*)(hg + NB_G * HD);                         // N
    int* bucket = counts + NN;                                    // N*BCAP (12.8 MB)

    int nblocks_e1024 = (NE + 1023) / 1024;  // 489 scatter blocks (1024 thr)
    int gemm1_blocks = (NN + 255) / 256;     // 196 (ROWS=256)
    int gemm2_blocks = (NN + 127) / 128;     // 391 (ROWS=128)
    int wave_node_blocks = (NN * 64 + 255) / 256;

    // prep: zero counts + transpose weights + zero hg
    prep_kernel<<<NB_CNT + INDIM + HD, 256, 0, stream>>>(counts, W1, W2, Wt1, Wt2, hg);

    // layer-1 gemm (K=128, fp32 input, 256-row tile) with fused bucket scatter
    gemm_mfma_kernel<INDIM, 1, 256, 1024><<<gemm1_blocks + nblocks_e1024, 1024, 0, stream>>>(
        h, Wt1, al1, ar1, zb, el, er, NN,
        gemm1_blocks, dst, src, counts, bucket, NE);
    agg_kernel<<<wave_node_blocks, 256, 0, stream>>>(zb, el, er, b1, counts, bucket, h1b, NN, 1);
    // layer 2 (K=256, bf16 input, 128-row tile — LDS-capped)
    gemm_mfma_kernel<HD, 0, 128, 512><<<gemm2_blocks, 512, 0, stream>>>(
        h1b, Wt2, al2, ar2, zb, el, er, NN,
        gemm2_blocks, nullptr, nullptr, nullptr, nullptr, 0);
    agg_kernel<<<wave_node_blocks, 256, 0, stream>>>(zb, el, er, b2, counts, bucket, h1b, NN, 0);

    // readout
    graph_sum_kernel<<<(NN + 63) / 64, 256, 0, stream>>>(h1b, gids, hg);
    classifier_kernel<<<NB_G, 64, 0, stream>>>(hg, perm, Wc, bc, gids, out);
}

// Round 25
// 204.584 us; speedup vs baseline: 1.0833x; 1.0009x over previous
//
#include <hip/hip_runtime.h>
#include <hip/hip_bf16.h>

#define NN 50000
#define NE 500000
#define INDIM 128
#define NH 8
#define DH 32
#define HD 256
#define NPERM 100
#define NB_G 64
#define NC 10
#define SLOPE 0.2f
#define BCAP 64   // bucket capacity per node; Poisson(10) max over 50K nodes ~32, 2x margin

typedef short bf16x8 __attribute__((ext_vector_type(8)));
typedef float f32x4 __attribute__((ext_vector_type(4)));

__device__ inline float bf2f(unsigned short u) {
    union { unsigned int i; float f; } x; x.i = ((unsigned int)u) << 16; return x.f;
}
__device__ inline unsigned short f2bf(float f) {
    __hip_bfloat16 h = __float2bfloat16(f);
    return *reinterpret_cast<unsigned short*>(&h);
}

// ---------------- prep: zero counts + weight transpose + hg zero ----------------

#define NB_CNT ((NN + 255) / 256)   // 196

__global__ __launch_bounds__(256) void prep_kernel(
    int* __restrict__ counts,
    const float* __restrict__ W1, const float* __restrict__ W2,
    __hip_bfloat16* __restrict__ Wt1, __hip_bfloat16* __restrict__ Wt2,
    float* __restrict__ hg)
{
    int b = blockIdx.x;
    int c = threadIdx.x;
    if (b < NB_CNT) {
        int i = b * 256 + c;
        if (i < NN) counts[i] = 0;
    } else {
        int bb = b - NB_CNT;   // 0..383
        if (bb < INDIM) {
            Wt1[(size_t)c * INDIM + bb] = __float2bfloat16(W1[(size_t)bb * HD + c]);
        } else {
            int k = bb - INDIM;
            Wt2[(size_t)c * HD + k] = __float2bfloat16(W2[(size_t)k * HD + c]);
        }
        if (bb < NB_G) hg[bb * HD + c] = 0.f;
    }
}

// ---------------- MFMA GEMM: ROWS x 256 cols, TPB threads, whole-panel LDS, single barrier ----------------
// R24 postmortem: gemm time invariant to partitioning at constant work; FETCH+WRITE / dur
// == measured hbm_gbps (~1.45 TB/s, write-dominated) -> gemm is write-path bound.
// R25: z stores become NON-TEMPORAL (z doesn't fit L2; avoid write-allocate pollution and
// stream straight out). el/er (1.6 MB, L2-resident, re-read by agg) stay cached.
// Wave (wr, wc): wr = wv>>2 (64-row group), wc = wv&3 (64-col strip); acc[4][4].
// A from LDS (slot p = logical q ^ (row&7)); B flat from L2-resident Wt.
// Blocks >= gemm_nblocks run the edge->bucket scatter (early return, no barrier).

template<int KVAL, int IS_F32, int ROWS, int TPB>
__global__ __launch_bounds__(TPB) void gemm_mfma_kernel(
    const void* __restrict__ Xv, const __hip_bfloat16* __restrict__ Wt,
    const float* __restrict__ al, const float* __restrict__ ar,
    __hip_bfloat16* __restrict__ zb, float* __restrict__ el, float* __restrict__ er,
    int nrows, int gemm_nblocks,
    const int* __restrict__ dstv, const int* __restrict__ srcv,
    int* __restrict__ counts, int* __restrict__ bucket, int ne)
{
    __shared__ __attribute__((aligned(16))) unsigned short Xs[ROWS * KVAL];   // <= 64 KB
    int t = threadIdx.x;

    if ((int)blockIdx.x >= gemm_nblocks) {
        // fused bucket scatter (block-uniform; never reaches the barrier)
        int e = ((int)blockIdx.x - gemm_nblocks) * TPB + t;
        if (e < ne) {
            int d = dstv[e];
            int p = atomicAdd(&counts[d], 1);
            if (p < BCAP) bucket[(size_t)d * BCAP + p] = srcv[e];
        }
        return;
    }

    int l = t & 63;
    int wv = t >> 6;
    int wr = wv >> 2;       // 64-row group
    int wc = wv & 3;        // 64-col strip
    int nb = blockIdx.x * ROWS;
    int wcb = wc * 64;
    int lg = l >> 4;
    int lr = l & 15;

    const short* Wt16 = (const short*)Wt;
    constexpr int NSLOT = KVAL / 8;       // 16B slots per A row
    constexpr int NKK = KVAL / 32;        // MFMA k-steps

    // ---- stage entire ROWS x K A panel (single shot); TPB/ROWS == 4 ----
    if (IS_F32) {
        const float* Xf = (const float*)Xv;
        int row = t >> 2;
        int gr = nb + row;
#pragma unroll
        for (int i = 0; i < NSLOT / 4; ++i) {
            int j = (t & 3) + 4 * i;
            bf16x8 xv = {0, 0, 0, 0, 0, 0, 0, 0};
            if (gr < nrows) {
                const float* p = &Xf[(size_t)gr * KVAL + j * 8];
                float4 xa = *(const float4*)&p[0];
                float4 xb = *(const float4*)&p[4];
                xv[0] = (short)f2bf(xa.x); xv[1] = (short)f2bf(xa.y);
                xv[2] = (short)f2bf(xa.z); xv[3] = (short)f2bf(xa.w);
                xv[4] = (short)f2bf(xb.x); xv[5] = (short)f2bf(xb.y);
                xv[6] = (short)f2bf(xb.z); xv[7] = (short)f2bf(xb.w);
            }
            *(bf16x8*)&Xs[row * KVAL + ((j ^ (row & 7)) * 8)] = xv;
        }
    } else {
        const short* X16 = (const short*)Xv;
#pragma unroll
        for (int i = 0; i < (ROWS * NSLOT) / TPB; ++i) {
            int c = t + i * TPB;
            int row = c / NSLOT;
            int p = c % NSLOT;
            int q = p ^ (row & 7);
            const short* ga = &X16[(size_t)(nb + row) * KVAL + q * 8];
            __builtin_amdgcn_global_load_lds(
                (const __attribute__((address_space(1))) void*)ga,
                (__attribute__((address_space(3))) void*)((char*)Xs + (size_t)c * 16), 16, 0, 0);
        }
    }
    __syncthreads();   // the single barrier

    // ---- MFMA loop, no barriers ----
    f32x4 acc[4][4];
#pragma unroll
    for (int rb = 0; rb < 4; ++rb)
#pragma unroll
        for (int cf = 0; cf < 4; ++cf) acc[rb][cf] = (f32x4){0.f, 0.f, 0.f, 0.f};

#pragma unroll
    for (int kk = 0; kk < NKK; ++kk) {
        bf16x8 b[4], a[4];
#pragma unroll
        for (int cf = 0; cf < 4; ++cf) {
            int col = wcb + cf * 16 + lr;
            b[cf] = *(const bf16x8*)&Wt16[(size_t)col * KVAL + kk * 32 + lg * 8];
        }
#pragma unroll
        for (int rb = 0; rb < 4; ++rb) {
            int row = wr * 64 + rb * 16 + lr;
            int slot = (kk * 4 + lg) ^ (row & 7);
            a[rb] = *(const bf16x8*)&Xs[row * KVAL + slot * 8];
        }
#pragma unroll
        for (int rb = 0; rb < 4; ++rb)
#pragma unroll
            for (int cf = 0; cf < 4; ++cf)
                acc[rb][cf] = __builtin_amdgcn_mfma_f32_16x16x32_bf16(a[rb], b[cf], acc[rb][cf], 0, 0, 0);
    }

    // ---- epilogue: z via NON-TEMPORAL stores; el/er normal (L2-resident, re-read) ----
    float al_c[4], ar_c[4];
#pragma unroll
    for (int cf = 0; cf < 4; ++cf) {
        al_c[cf] = al[wcb + cf * 16 + lr];
        ar_c[cf] = ar[wcb + cf * 16 + lr];
    }

    unsigned short* zu = (unsigned short*)zb;
#pragma unroll
    for (int rb = 0; rb < 4; ++rb) {
        int rbase = nb + wr * 64 + rb * 16 + lg * 4;
#pragma unroll
        for (int j = 0; j < 4; ++j) {
            int r = rbase + j;
            if (r < nrows) {
#pragma unroll
                for (int cf = 0; cf < 4; ++cf)
                    __builtin_nontemporal_store(f2bf(acc[rb][cf][j]),
                                                &zu[(size_t)r * HD + wcb + cf * 16 + lr]);
            }
        }
        float p0[4], p1[4], q0[4], q1[4];
#pragma unroll
        for (int j = 0; j < 4; ++j) {
            p0[j] = acc[rb][0][j] * al_c[0] + acc[rb][1][j] * al_c[1];
            p1[j] = acc[rb][2][j] * al_c[2] + acc[rb][3][j] * al_c[3];
            q0[j] = acc[rb][0][j] * ar_c[0] + acc[rb][1][j] * ar_c[1];
            q1[j] = acc[rb][2][j] * ar_c[2] + acc[rb][3][j] * ar_c[3];
        }
#pragma unroll
        for (int m = 1; m < 16; m <<= 1) {
#pragma unroll
            for (int j = 0; j < 4; ++j) {
                p0[j] += __shfl_xor(p0[j], m);
                p1[j] += __shfl_xor(p1[j], m);
                q0[j] += __shfl_xor(q0[j], m);
                q1[j] += __shfl_xor(q1[j], m);
            }
        }
        if (lr == 0) {
#pragma unroll
            for (int j = 0; j < 4; ++j) {
                int r = rbase + j;
                if (r < nrows) {
                    el[(size_t)r * NH + 2 * wc]     = p0[j];
                    el[(size_t)r * NH + 2 * wc + 1] = p1[j];
                    er[(size_t)r * NH + 2 * wc]     = q0[j];
                    er[(size_t)r * NH + 2 * wc + 1] = q1[j];
                }
            }
        }
    }
}

// ---------------- per-dst-node attention aggregate (R9 structure = proven floor) ----------------

__global__ __launch_bounds__(256) void agg_kernel(
    const __hip_bfloat16* __restrict__ zb, const float* __restrict__ el, const float* __restrict__ er,
    const float* __restrict__ bias, const int* __restrict__ counts,
    const int* __restrict__ bucket, __hip_bfloat16* __restrict__ out, int nrows, int do_relu)
{
    int wid = (blockIdx.x * 256 + threadIdx.x) >> 6;
    int l = threadIdx.x & 63;
    if (wid >= nrows) return;   // wave-uniform
    int n = wid;
    int K = counts[n];
    if (K > BCAP) K = BCAP;
    const int* srcs = &bucket[(size_t)n * BCAP];
    const unsigned short* zu = (const unsigned short*)zb;

    int es = l >> 4;   // edge slot 0..3
    int li = l & 15;   // channel group: c0 = li*16
    int hh = li >> 1;  // head
    float ern = er[(size_t)n * NH + hh];
    int c0 = li * 16;

    float num[16];
#pragma unroll
    for (int j = 0; j < 16; ++j) num[j] = 0.f;
    float den = 0.f;

    for (int kb = 0; kb < K; kb += 4) {
        int k = kb + es;
        if (k < K) {
            int s = srcs[k];
            float v = el[(size_t)s * NH + hh] + ern;
            v = v > 0.f ? v : SLOPE * v;
            float w = __expf(v);
            den += w;
            const unsigned short* zr = &zu[(size_t)s * HD + c0];
            bf16x8 z0 = *(const bf16x8*)&zr[0];
            bf16x8 z1 = *(const bf16x8*)&zr[8];
#pragma unroll
            for (int j = 0; j < 8; ++j) {
                num[j]     += w * bf2f((unsigned short)z0[j]);
                num[8 + j] += w * bf2f((unsigned short)z1[j]);
            }
        }
    }

    den += __shfl_xor(den, 16);
    den += __shfl_xor(den, 32);
#pragma unroll
    for (int j = 0; j < 16; ++j) {
        num[j] += __shfl_xor(num[j], 16);
        num[j] += __shfl_xor(num[j], 32);
    }

    if (es == 0) {
        float inv = (K > 0) ? 1.0f / den : 0.f;   // deg-0 node -> out = bias
        unsigned short* op = (unsigned short*)out;
        float4 bva = *(const float4*)&bias[c0];
        float4 bvb = *(const float4*)&bias[c0 + 4];
        float4 bvc = *(const float4*)&bias[c0 + 8];
        float4 bvd = *(const float4*)&bias[c0 + 12];
        float bb[16] = {bva.x, bva.y, bva.z, bva.w, bvb.x, bvb.y, bvb.z, bvb.w,
                        bvc.x, bvc.y, bvc.z, bvc.w, bvd.x, bvd.y, bvd.z, bvd.w};
        bf16x8 o0, o1;
#pragma unroll
        for (int j = 0; j < 8; ++j) {
            float v0 = num[j] * inv + bb[j];
            float v1 = num[8 + j] * inv + bb[8 + j];
            if (do_relu) { v0 = fmaxf(v0, 0.f); v1 = fmaxf(v1, 0.f); }
            o0[j] = (short)f2bf(v0);
            o1[j] = (short)f2bf(v1);
        }
        *(bf16x8*)&op[(size_t)n * HD + c0] = o0;
        *(bf16x8*)&op[(size_t)n * HD + c0 + 8] = o1;
    }
}

// ---------------- readout ----------------

__global__ __launch_bounds__(256) void graph_sum_kernel(
    const __hip_bfloat16* __restrict__ h2, const int* __restrict__ gids,
    float* __restrict__ hg)
{
    int c = threadIdx.x;
    int n0 = blockIdx.x * 64;
    int n1 = n0 + 64;
    if (n0 >= NN) return;
    if (n1 > NN) n1 = NN;
    const unsigned short* hu = (const unsigned short*)h2;
    float acc = 0.f;
    int cur = gids[n0];
    for (int n = n0; n < n1; ++n) {
        int g = gids[n];
        if (g != cur) {
            atomicAdd(&hg[cur * HD + c], acc);
            acc = 0.f;
            cur = g;
        }
        acc += bf2f(hu[(size_t)n * HD + c]);
    }
    atomicAdd(&hg[cur * HD + c], acc);
}

__global__ void classifier_kernel(const float* __restrict__ hg, const float* __restrict__ perm,
                                  const float* __restrict__ Wc, const float* __restrict__ bc,
                                  const int* __restrict__ gids, float* __restrict__ out) {
    int g = blockIdx.x;
    int c = threadIdx.x;
    if (c >= NC) return;
    int lo = 0, hi = NN;
    while (lo < hi) { int mid = (lo + hi) >> 1; if (gids[mid] < g) lo = mid + 1; else hi = mid; }
    int s0 = lo;
    lo = 0; hi = NN;
    while (lo < hi) { int mid = (lo + hi) >> 1; if (gids[mid] < g + 1) lo = mid + 1; else hi = mid; }
    float cnt = fmaxf((float)(lo - s0), 1.0f);
    float inv = 1.0f / cnt;
    float sg = 0.f;
    for (int k = 0; k < HD; ++k) sg += hg[g * HD + k] * Wc[k * NC + c];
    float s = bc[c] + sg * inv;
    for (int k = 0; k < NPERM; ++k) s += perm[g * NPERM + k] * Wc[(HD + k) * NC + c];
    out[g * NC + c] = s;
}

// ---------------- launch ----------------

extern "C" void kernel_launch(void* const* d_in, const int* in_sizes, int n_in,
                              void* d_out, int out_size, void* d_ws, size_t ws_size,
                              hipStream_t stream) {
    const float* h    = (const float*)d_in[0];
    const float* perm = (const float*)d_in[1];
    const float* W1   = (const float*)d_in[2];
    const float* al1  = (const float*)d_in[3];
    const float* ar1  = (const float*)d_in[4];
    const float* b1   = (const float*)d_in[5];
    const float* W2   = (const float*)d_in[6];
    const float* al2  = (const float*)d_in[7];
    const float* ar2  = (const float*)d_in[8];
    const float* b2   = (const float*)d_in[9];
    const float* Wc   = (const float*)d_in[10];
    const float* bc   = (const float*)d_in[11];
    const int* src    = (const int*)d_in[12];
    const int* dst    = (const int*)d_in[13];
    const int* gids   = (const int*)d_in[14];
    float* out = (float*)d_out;

    __hip_bfloat16* zb  = (__hip_bfloat16*)d_ws;                  // N*256
    __hip_bfloat16* h1b = zb + (size_t)NN * HD;                   // N*256
    __hip_bfloat16* Wt1 = h1b + (size_t)NN * HD;                  // 256*128
    __hip_bfloat16* Wt2 = Wt1 + (size_t)HD * INDIM;               // 256*256
    float* el = (float*)(Wt2 + (size_t)HD * HD);                  // N*8
    float* er = el + (size_t)NN * NH;                             // N*8
    float* hg = er + (size_t)NN * NH;                             // B*256
    int* counts = (int*)(hg + NB_G * HD);                         // N
    int* bucket = counts + NN;                                    // N*BCAP (12.8 MB)

    int nblocks_e1024 = (NE + 1023) / 1024;  // 489 scatter blocks (1024 thr)
    int gemm1_blocks = (NN + 255) / 256;     // 196 (ROWS=256)
    int gemm2_blocks = (NN + 127) / 128;     // 391 (ROWS=128)
    int wave_node_blocks = (NN * 64 + 255) / 256;

    // prep: zero counts + transpose weights + zero hg
    prep_kernel<<<NB_CNT + INDIM + HD, 256, 0, stream>>>(counts, W1, W2, Wt1, Wt2, hg);

    // layer-1 gemm (K=128, fp32 input, 256-row tile) with fused bucket scatter
    gemm_mfma_kernel<INDIM, 1, 256, 1024><<<gemm1_blocks + nblocks_e1024, 1024, 0, stream>>>(
        h, Wt1, al1, ar1, zb, el, er, NN,
        gemm1_blocks, dst, src, counts, bucket, NE);
    agg_kernel<<<wave_node_blocks, 256, 0, stream>>>(zb, el, er, b1, counts, bucket, h1b, NN, 1);
    // layer 2 (K=256, bf16 input, 128-row tile — LDS-capped)
    gemm_mfma_kernel<HD, 0, 128, 512><<<gemm2_blocks, 512, 0, stream>>>(
        h1b, Wt2, al2, ar2, zb, el, er, NN,
        gemm2_blocks, nullptr, nullptr, nullptr, nullptr, 0);
    agg_kernel<<<wave_node_blocks, 256, 0, stream>>>(zb, el, er, b2, counts, bucket, h1b, NN, 0);

    // readout
    graph_sum_kernel<<<(NN + 63) / 64, 256, 0, stream>>>(h1b, gids, hg);
    classifier_kernel<<<NB_G, 64, 0, stream>>>(hg, perm, Wc, bc, gids, out);
}